// Round 2
// baseline (345.585 us; speedup 1.0000x reference)
//
#include <hip/hip_runtime.h>
#include <hip/hip_bf16.h>

// CausalSelfAttention on MI355X (gfx950).
// B=2, S=2048, HIDDEN=2048, H=16 heads, D=128, Hkv=4 (GQA groups=4).
// Round 10: flash_attn arithmetic-intensity doubling. R9 analysis: LDS pipe ~62%
//   busy (34 ds_read_b128 per 32 MFMAs) is the dominant pipe; MfmaUtil capped
//   at ~17%. Fix: each wave owns 32 q-rows (two 16-row groups). K-frag and
//   V-frag LDS reads are IDENTICAL for both groups -> each read feeds 2 MFMAs:
//   36 b128 reads per 64 MFMAs (2x intensity). Block = 4 waves x 32 rows =
//   same 128-row q-tile, 256 threads, same 54,272 B LDS -> 2 complementary-
//   paired blocks/CU (8 waves/CU) as before. Mask int4 shared by both groups.
//   Keeps R9's permuted-K staging (P written as one b64/row), vf-hoist above
//   the P drain, and setprio around MFMA clusters.
//
// MFMA layouts (HW-verified per guide m89/m91/m120):
//   A frag: A[m=lane&15][k=(lane>>4)*8 + j], j=0..7  (16B contiguous in K)
//   B frag: B^T stored [n][k], same addressing as A
//   C/D   : col=lane&15, row=(lane>>4)*4 + reg

typedef unsigned short u16;
typedef __attribute__((ext_vector_type(8))) short short8;   // 8 x bf16 (4 VGPRs)
typedef __attribute__((ext_vector_type(4))) float f32x4;

#define BATCH 2
#define SEQ 2048
#define HIDDEN 2048
#define NH 16
#define NKV 4
#define HD 128
#define QKV_N 3072   // 2048 q + 512 k + 512 v
#define MROWS 4096   // BATCH*SEQ

__device__ inline u16 f2bf(float f) {
    __hip_bfloat16 h = __float2bfloat16(f);
    return __builtin_bit_cast(u16, h);
}

// async global->LDS, 16B per lane; lds base must be wave-uniform (HW adds lane*16)
__device__ inline void async_copy16(const u16* g, u16* lds_base) {
    __builtin_amdgcn_global_load_lds(
        (const __attribute__((address_space(1))) void*)g,
        (__attribute__((address_space(3))) void*)lds_base, 16, 0, 0);
}

// ---------------- elementwise convert fp32 -> bf16 ----------------
__global__ void convert_f32_bf16(const float* __restrict__ src, u16* __restrict__ dst, int n) {
    int i = (blockIdx.x * 256 + threadIdx.x) * 4;
    if (i + 3 < n) {
        float4 v = *(const float4*)(src + i);
        ushort4 o;
        o.x = f2bf(v.x); o.y = f2bf(v.y); o.z = f2bf(v.z); o.w = f2bf(v.w);
        *(ushort4*)(dst + i) = o;
    }
}

// ---------------- transpose-convert: src[K][N] fp32 -> dst[N][K] bf16 ----------------
__global__ void transpose_f32_bf16(const float* __restrict__ src, u16* __restrict__ dst,
                                   int K, int N) {
    __shared__ float tile[32][33];
    int n0 = blockIdx.x * 32, k0 = blockIdx.y * 32;
    int tx = threadIdx.x, ty = threadIdx.y;
#pragma unroll
    for (int i = 0; i < 32; i += 8)
        tile[ty + i][tx] = src[(size_t)(k0 + ty + i) * N + n0 + tx];
    __syncthreads();
#pragma unroll
    for (int i = 0; i < 32; i += 8)
        dst[(size_t)(n0 + ty + i) * K + k0 + tx] = f2bf(tile[tx][ty + i]);
}

// ---------------- fused qkv bias ----------------
__global__ void build_bias(const float* __restrict__ bq, const float* __restrict__ bk,
                           const float* __restrict__ bv, float* __restrict__ bqkv) {
    int i = blockIdx.x * 256 + threadIdx.x;
    if (i < QKV_N)
        bqkv[i] = (i < 2048) ? bq[i] : ((i < 2560) ? bk[i - 2048] : bv[i - 2560]);
}

// ---------------- V^T extraction from qkv buffer ----------------
// qkv row stride 3072; v at col 2560 + kvh*128 + d. VT layout: [b][kvh][d=128][s=2048]
__global__ void vt_from_qkv(const u16* __restrict__ qkv, u16* __restrict__ vt) {
    __shared__ u16 tile[32][33];
    int b = blockIdx.z >> 2, kvh = blockIdx.z & 3;
    int s0 = blockIdx.x * 32, d0 = blockIdx.y * 32;
    int tx = threadIdx.x, ty = threadIdx.y;
#pragma unroll
    for (int i = 0; i < 32; i += 8)
        tile[ty + i][tx] = qkv[(size_t)(b * SEQ + s0 + ty + i) * QKV_N + 2560 + kvh * HD + d0 + tx];
    __syncthreads();
#pragma unroll
    for (int i = 0; i < 32; i += 8)
        vt[(size_t)((b * NKV + kvh) * HD + d0 + ty + i) * SEQ + s0 + tx] = tile[tx][ty + i];
}

// ---------------- bf16 GEMM (m97 structure): out[M][N] = A[M][K] @ BT[N][K]^T + bias ----
// 128x128 tile, BK=32, 256 threads = 4 waves in 2x2; each wave 64x64 via 4x4 acc.
template <bool OUT_BF16>
__global__ __launch_bounds__(256)
void gemm_bf16_128(const u16* __restrict__ A, const u16* __restrict__ BT,
                   const float* __restrict__ bias, void* __restrict__ outp,
                   int M, int N, int K) {
    __shared__ __align__(16) u16 As[128][32];   // no pad: global_load_lds needs contiguous
    __shared__ __align__(16) u16 Bs[128][32];
    int t = threadIdx.x, w = t >> 6, lane = t & 63, quad = lane >> 4, l16 = lane & 15;
    int wm = w & 1, wn = w >> 1;
    int bm0 = blockIdx.y * 128, bn0 = blockIdx.x * 128;

    f32x4 acc[4][4];
#pragma unroll
    for (int i = 0; i < 4; i++)
#pragma unroll
        for (int j = 0; j < 4; j++) acc[i][j] = (f32x4){0.f, 0.f, 0.f, 0.f};

    for (int k0 = 0; k0 < K; k0 += 32) {
        __syncthreads();  // previous iter's LDS reads done
#pragma unroll
        for (int j = 0; j < 2; j++) {
            int f = (w * 2 + j) * 64 + lane;      // 0..511 (16B chunks)
            int row = f >> 2, col = (f & 3) * 8;  // 4 chunks of 8 bf16 per 32-col row
            u16* abase = &As[0][0] + (size_t)(w * 2 + j) * 512;  // wave-uniform
            u16* bbase = &Bs[0][0] + (size_t)(w * 2 + j) * 512;
            async_copy16(A + (size_t)(bm0 + row) * K + k0 + col, abase);
            async_copy16(BT + (size_t)(bn0 + row) * K + k0 + col, bbase);
        }
        __syncthreads();  // compiler drains vmcnt before barrier
        short8 af[4], bf[4];
#pragma unroll
        for (int mt = 0; mt < 4; mt++) af[mt] = *(const short8*)(&As[wm * 64 + mt * 16 + l16][quad * 8]);
#pragma unroll
        for (int nt = 0; nt < 4; nt++) bf[nt] = *(const short8*)(&Bs[wn * 64 + nt * 16 + l16][quad * 8]);
#pragma unroll
        for (int mt = 0; mt < 4; mt++)
#pragma unroll
            for (int nt = 0; nt < 4; nt++)
                acc[mt][nt] = __builtin_amdgcn_mfma_f32_16x16x32_bf16(af[mt], bf[nt], acc[mt][nt], 0, 0, 0);
    }
#pragma unroll
    for (int nt = 0; nt < 4; nt++) {
        int col = bn0 + wn * 64 + nt * 16 + l16;
        float bcol = bias[col];
#pragma unroll
        for (int mt = 0; mt < 4; mt++) {
#pragma unroll
            for (int r = 0; r < 4; r++) {
                int row = bm0 + wm * 64 + mt * 16 + quad * 4 + r;
                float v = acc[mt][nt][r] + bcol;
                if constexpr (OUT_BF16)
                    ((u16*)outp)[(size_t)row * N + col] = f2bf(v);
                else
                    ((float*)outp)[(size_t)row * N + col] = v;
            }
        }
    }
}

// ---------------- flash attention (causal, GQA), fixed-shift softmax --------
// grid (S/128, NH, BATCH), 256 threads = 4 waves; wave w owns 32 q rows
// (two 16-row groups) at qt*128 + w*32. qt derived so blocks id and id+256
// (same CU under the typical mod-256 mapping) have COMPLEMENTARY causal work:
// qt = bz ? G-1-bx : bx; 2 blocks/CU (54.3 KB LDS each).
// K tile staged with row permutation pi(r) = 4*(r&15) + (r>>4): score tile nt,
// lane l16 owns key kb + 4*l16 + nt -> lane's 4 P values consecutive -> one
// ds_write_b64 per row; P lands in natural key order for the PV A-fragments.
// K-frag and V-frag reads are SHARED by both row groups (2 MFMAs per read).
// Fixed-shift softmax (shift-invariance; scores bounded) -> no in-loop
// cross-lane ops; per-lane partial row-sums reduced once in the epilogue.
// Pads: Ks rows 272B, Vs 144B, Pb 144B -- 16B-aligned odd multiples of 16B.
__global__ __launch_bounds__(256, 2)
void flash_attn(const u16* __restrict__ qkv, const u16* __restrict__ vt,
                const int* __restrict__ amask, u16* __restrict__ attn) {
    __shared__ __align__(16) u16 Ks[64][136];   // 128 + 8 pad
    __shared__ __align__(16) u16 Vs[128][72];   // 64 + 8 pad
    __shared__ __align__(16) u16 Pb[4][32][72]; // per-wave P tile: 32 rows x 64 keys
    int t = threadIdx.x, w = t >> 6, lane = t & 63, quad = lane >> 4, l16 = lane & 15;
    int bx = blockIdx.x, b = blockIdx.z;
    int qt = b ? ((int)gridDim.x - 1 - bx) : bx;    // complementary pairing
    int h = blockIdx.y, kvh = h >> 2;
    int q_row0 = qt * 128 + w * 32;
    u16(*P)[72] = Pb[w];

    // Q fragments for both 16-row groups: rows q_row0 + g*16 + l16
    short8 qf[2][4];
#pragma unroll
    for (int g = 0; g < 2; g++) {
        const u16* qrow = qkv + (size_t)(b * SEQ + q_row0 + g * 16 + l16) * QKV_N + h * HD;
#pragma unroll
        for (int c = 0; c < 4; c++) qf[g][c] = *(const short8*)(qrow + c * 32 + quad * 8);
    }

    f32x4 o[2][8];
#pragma unroll
    for (int g = 0; g < 2; g++)
#pragma unroll
        for (int dt = 0; dt < 8; dt++) o[g][dt] = (f32x4){0.f, 0.f, 0.f, 0.f};
    float lpart[2][4] = {{0.f, 0.f, 0.f, 0.f}, {0.f, 0.f, 0.f, 0.f}};

    // exp(score*scale - 10) == exp2(score*scale2 - C2); ratio to l is shift-invariant.
    const float scale2 = 0.12751743f;   // (1/sqrt(128)) * log2(e)
    const float C2 = 14.4269504f;       // 10 * log2(e)

    const u16* kgb = qkv + (size_t)(b * SEQ) * QKV_N + 2048 + kvh * HD;
    const u16* vgb = vt + (size_t)((b * NKV + kvh) * HD) * SEQ;
    const int* am = amask + b * SEQ;

    // staging (256 threads, 4 chunks each for K and V):
    // K: thread t covers LDS rows kr+16j (j=0..3) = source keys 4*kr + j at col kc.
    // V: thread t covers rows vr+32j at col vc.
    int kr = t >> 4, kc = (t & 15) * 8;   // K: 16 chunks per 128-col row
    int ksrc = 4 * kr;                    // pi(kr+16j) = 4*kr + j
    int vr = t >> 3, vc = (t & 7) * 8;    // V: 8 chunks per 64-col row
    int kb_end = (qt + 1) * 128;

    short8 kp[4], vp[4];
#pragma unroll
    for (int j = 0; j < 4; j++) {
        kp[j] = *(const short8*)(kgb + (size_t)(ksrc + j) * QKV_N + kc);
        vp[j] = *(const short8*)(vgb + (size_t)(vr + 32 * j) * SEQ + vc);
    }

    for (int kb = 0; kb < kb_end; kb += 64) {
        __syncthreads();  // previous iter's LDS reads done
#pragma unroll
        for (int j = 0; j < 4; j++) {
            *(short8*)(&Ks[kr + 16 * j][kc]) = kp[j];
            *(short8*)(&Vs[vr + 32 * j][vc]) = vp[j];
        }
        __syncthreads();
        if (kb + 64 < kb_end) {  // prefetch next tile during compute (T14 issue-early)
            const u16* kg = kgb + (size_t)(kb + 64) * QKV_N;
            const u16* vg = vgb + kb + 64;
#pragma unroll
            for (int j = 0; j < 4; j++) {
                kp[j] = *(const short8*)(kg + (size_t)(ksrc + j) * QKV_N + kc);
                vp[j] = *(const short8*)(vg + (size_t)(vr + 32 * j) * SEQ + vc);
            }
        }
        if (kb > q_row0 + 31) continue;  // wave-uniform: no keys for this wave's rows

        // ---- scores: four 16x16 key tiles per group; kf SHARED by both groups
        f32x4 sc[2][4];
#pragma unroll
        for (int g = 0; g < 2; g++)
#pragma unroll
            for (int nt = 0; nt < 4; nt++) sc[g][nt] = (f32x4){0.f, 0.f, 0.f, 0.f};
        __builtin_amdgcn_s_setprio(1);
#pragma unroll
        for (int c = 0; c < 4; c++) {
#pragma unroll
            for (int nt = 0; nt < 4; nt++) {
                short8 kf = *(const short8*)(&Ks[nt * 16 + l16][c * 32 + quad * 8]);
                sc[0][nt] = __builtin_amdgcn_mfma_f32_16x16x32_bf16(qf[0][c], kf, sc[0][nt], 0, 0, 0);
                sc[1][nt] = __builtin_amdgcn_mfma_f32_16x16x32_bf16(qf[1][c], kf, sc[1][nt], 0, 0, 0);
            }
        }
        __builtin_amdgcn_s_setprio(0);

        // ---- mask + fixed-shift exp; lane owns keys kbase..kbase+3 (both groups)
        int kbase = kb + 4 * l16;
        int4 mk = *(const int4*)(am + kbase);   // 16B aligned: kb%64==0
#pragma unroll
        for (int g = 0; g < 2; g++) {
#pragma unroll
            for (int r = 0; r < 4; r++) {
                int qi = q_row0 + g * 16 + quad * 4 + r;
                float v0 = (mk.x && kbase     <= qi) ? sc[g][0][r] : -INFINITY;
                float v1 = (mk.y && kbase + 1 <= qi) ? sc[g][1][r] : -INFINITY;
                float v2 = (mk.z && kbase + 2 <= qi) ? sc[g][2][r] : -INFINITY;
                float v3 = (mk.w && kbase + 3 <= qi) ? sc[g][3][r] : -INFINITY;
                float p0 = __builtin_exp2f(__builtin_fmaf(v0, scale2, -C2));
                float p1 = __builtin_exp2f(__builtin_fmaf(v1, scale2, -C2));
                float p2 = __builtin_exp2f(__builtin_fmaf(v2, scale2, -C2));
                float p3 = __builtin_exp2f(__builtin_fmaf(v3, scale2, -C2));
                lpart[g][r] += (p0 + p1) + (p2 + p3);
                uint2 pk;
                pk.x = (unsigned)f2bf(p0) | ((unsigned)f2bf(p1) << 16);
                pk.y = (unsigned)f2bf(p2) | ((unsigned)f2bf(p3) << 16);
                *(uint2*)(&P[g * 16 + quad * 4 + r][4 * l16]) = pk;  // 8B store
            }
        }
        // hoist first half of keys-0..31 V fragments above the P drain: independent
        // of P, so they complete during the P write->read round trip.
        short8 vf0a[4];
#pragma unroll
        for (int dt = 0; dt < 4; dt++)
            vf0a[dt] = *(const short8*)(&Vs[dt * 16 + l16][quad * 8]);
        // wave-internal LDS write->read ordering for P (waves don't share P)
        asm volatile("s_waitcnt lgkmcnt(0)" ::: "memory");
        short8 pf00 = *(const short8*)(&P[l16][quad * 8]);        // g0, keys 0..31
        short8 pf01 = *(const short8*)(&P[l16][32 + quad * 8]);   // g0, keys 32..63
        short8 pf10 = *(const short8*)(&P[16 + l16][quad * 8]);   // g1, keys 0..31
        short8 pf11 = *(const short8*)(&P[16 + l16][32 + quad * 8]);
        __builtin_amdgcn_s_setprio(1);
#pragma unroll
        for (int dt = 0; dt < 4; dt++) {
            o[0][dt] = __builtin_amdgcn_mfma_f32_16x16x32_bf16(pf00, vf0a[dt], o[0][dt], 0, 0, 0);
            o[1][dt] = __builtin_amdgcn_mfma_f32_16x16x32_bf16(pf10, vf0a[dt], o[1][dt], 0, 0, 0);
        }
#pragma unroll
        for (int dt = 4; dt < 8; dt++) {
            short8 vf0 = *(const short8*)(&Vs[dt * 16 + l16][quad * 8]);
            o[0][dt] = __builtin_amdgcn_mfma_f32_16x16x32_bf16(pf00, vf0, o[0][dt], 0, 0, 0);
            o[1][dt] = __builtin_amdgcn_mfma_f32_16x16x32_bf16(pf10, vf0, o[1][dt], 0, 0, 0);
        }
#pragma unroll
        for (int dt = 0; dt < 8; dt++) {
            short8 vf1 = *(const short8*)(&Vs[dt * 16 + l16][32 + quad * 8]);
            o[0][dt] = __builtin_amdgcn_mfma_f32_16x16x32_bf16(pf01, vf1, o[0][dt], 0, 0, 0);
            o[1][dt] = __builtin_amdgcn_mfma_f32_16x16x32_bf16(pf11, vf1, o[1][dt], 0, 0, 0);
        }
        __builtin_amdgcn_s_setprio(0);
    }
    // epilogue: reduce per-lane partial sums across the 16 lanes of each row group
    float inv[2][4];
#pragma unroll
    for (int g = 0; g < 2; g++)
#pragma unroll
        for (int r = 0; r < 4; r++) {
            float l = lpart[g][r];
#pragma unroll
            for (int off = 1; off < 16; off <<= 1) l += __shfl_xor(l, off, 64);
            inv[g][r] = l > 0.f ? 1.f / l : 0.f;
        }
#pragma unroll
    for (int g = 0; g < 2; g++) {
        size_t obase = (size_t)(b * SEQ + q_row0 + g * 16) * HIDDEN + h * HD;
#pragma unroll
        for (int dt = 0; dt < 8; dt++)
#pragma unroll
            for (int r = 0; r < 4; r++)
                attn[obase + (size_t)(quad * 4 + r) * HIDDEN + dt * 16 + l16] =
                    f2bf(o[g][dt][r] * inv[g][r]);
    }
}

extern "C" void kernel_launch(void* const* d_in, const int* in_sizes, int n_in,
                              void* d_out, int out_size, void* d_ws, size_t ws_size,
                              hipStream_t stream) {
    const float* hidden = (const float*)d_in[0];
    const int* amask   = (const int*)d_in[1];
    const float* Wq = (const float*)d_in[2];
    const float* bq = (const float*)d_in[3];
    const float* Wk = (const float*)d_in[4];
    const float* bk = (const float*)d_in[5];
    const float* Wv = (const float*)d_in[6];
    const float* bv = (const float*)d_in[7];
    const float* Wo = (const float*)d_in[8];
    const float* bo = (const float*)d_in[9];
    float* out = (float*)d_out;

    // workspace layout (~84 MB)
    char* ws = (char*)d_ws;
    u16* xb     = (u16*)ws;  ws += (size_t)MROWS * HIDDEN * 2;        // 16.8 MB
    u16* wqkvT  = (u16*)ws;  ws += (size_t)QKV_N * HIDDEN * 2;       // 12.6 MB
    u16* woT    = (u16*)ws;  ws += (size_t)HIDDEN * HIDDEN * 2;      // 8.4 MB
    float* bqkv = (float*)ws; ws += (size_t)QKV_N * 4;               // 12 KB
    u16* qkv    = (u16*)ws;  ws += (size_t)MROWS * QKV_N * 2;        // 25.2 MB
    u16* vt     = (u16*)ws;  ws += (size_t)BATCH * NKV * HD * SEQ * 2; // 4.2 MB
    u16* attn   = (u16*)ws;  ws += (size_t)MROWS * HIDDEN * 2;       // 16.8 MB

    // 1. converts
    convert_f32_bf16<<<dim3(MROWS * HIDDEN / 1024), dim3(256), 0, stream>>>(hidden, xb, MROWS * HIDDEN);
    transpose_f32_bf16<<<dim3(64, 64), dim3(32, 8), 0, stream>>>(Wq, wqkvT, HIDDEN, 2048);
    transpose_f32_bf16<<<dim3(16, 64), dim3(32, 8), 0, stream>>>(Wk, wqkvT + (size_t)2048 * HIDDEN, HIDDEN, 512);
    transpose_f32_bf16<<<dim3(16, 64), dim3(32, 8), 0, stream>>>(Wv, wqkvT + (size_t)2560 * HIDDEN, HIDDEN, 512);
    transpose_f32_bf16<<<dim3(64, 64), dim3(32, 8), 0, stream>>>(Wo, woT, HIDDEN, HIDDEN);
    build_bias<<<dim3(12), dim3(256), 0, stream>>>(bq, bk, bv, bqkv);

    // 2. fused QKV projection (128x128 tile)
    gemm_bf16_128<true><<<dim3(QKV_N / 128, MROWS / 128), dim3(256), 0, stream>>>(
        xb, wqkvT, bqkv, qkv, MROWS, QKV_N, HIDDEN);

    // 3. V^T
    vt_from_qkv<<<dim3(SEQ / 32, HD / 32, BATCH * NKV), dim3(32, 8), 0, stream>>>(qkv, vt);

    // 4. attention (128 q rows per block, 4 waves x 32 rows, complementary pairing)
    flash_attn<<<dim3(SEQ / 128, NH, BATCH), dim3(256), 0, stream>>>(qkv, vt, amask, attn);

    // 5. output projection (fp32 out)
    gemm_bf16_128<false><<<dim3(HIDDEN / 128, MROWS / 128), dim3(256), 0, stream>>>(
        attn, woT, bo, out, MROWS, HIDDEN, HIDDEN);
}

// Round 3
// 328.910 us; speedup vs baseline: 1.0507x; 1.0507x over previous
//
#include <hip/hip_runtime.h>
#include <hip/hip_bf16.h>

// CausalSelfAttention on MI355X (gfx950).
// B=2, S=2048, HIDDEN=2048, H=16 heads, D=128, Hkv=4 (GQA groups=4).
// Round 11: flash_attn T12 in-register softmax path. R10 post-mortem: kernel is
//   latency-bound on the per-iter serial chain; halving waves/CU regressed.
//   Revert to R9's 512-thread / 8-wave / 16-rows-per-wave / paired-block
//   structure (16 waves/CU) and SHORTEN the chain:
//   - Swapped QK^T: mfma(kf, qf) -> lane holds S^T fragment: S[key][qrow=l16];
//     all 16 P values of a lane belong to ONE q-row.
//   - P -> PV A-fragment via in-register redistribution (T12): 8 cvt_pk_bf16
//     + 4x(permlane32_swap + permlane16_swap); no Pb LDS, no lgkmcnt(0) drain,
//     no P reads. LDS drops 54.3 -> 35.8 KB.
//   - K staged in natural row order (permutation was only for the P-write).
//   - attention_mask pre-packed to bits (pack_mask kernel); flash_attn loads
//     ONE wave-uniform u64 per 64-key tile (scalar path) instead of int4 loads.
//   - Row-sum: single per-lane accumulator; epilogue 2 shfl_xor + 4 shfl.
//
// MFMA layouts (HW-verified per guide m89/m91/m120):
//   A frag: A[m=lane&15][k=(lane>>4)*8 + j], j=0..7  (16B contiguous in K)
//   B frag: B^T stored [n][k], same addressing as A
//   C/D   : col=lane&15, row=(lane>>4)*4 + reg

typedef unsigned short u16;
typedef unsigned long long u64;
typedef __attribute__((ext_vector_type(8))) short short8;   // 8 x bf16 (4 VGPRs)
typedef __attribute__((ext_vector_type(4))) float f32x4;
typedef __attribute__((ext_vector_type(4))) unsigned uint4v;

#define BATCH 2
#define SEQ 2048
#define HIDDEN 2048
#define NH 16
#define NKV 4
#define HD 128
#define QKV_N 3072   // 2048 q + 512 k + 512 v
#define MROWS 4096   // BATCH*SEQ

__device__ inline u16 f2bf(float f) {
    __hip_bfloat16 h = __float2bfloat16(f);
    return __builtin_bit_cast(u16, h);
}

// async global->LDS, 16B per lane; lds base must be wave-uniform (HW adds lane*16)
__device__ inline void async_copy16(const u16* g, u16* lds_base) {
    __builtin_amdgcn_global_load_lds(
        (const __attribute__((address_space(1))) void*)g,
        (__attribute__((address_space(3))) void*)lds_base, 16, 0, 0);
}

// ---------------- elementwise convert fp32 -> bf16 ----------------
__global__ void convert_f32_bf16(const float* __restrict__ src, u16* __restrict__ dst, int n) {
    int i = (blockIdx.x * 256 + threadIdx.x) * 4;
    if (i + 3 < n) {
        float4 v = *(const float4*)(src + i);
        ushort4 o;
        o.x = f2bf(v.x); o.y = f2bf(v.y); o.z = f2bf(v.z); o.w = f2bf(v.w);
        *(ushort4*)(dst + i) = o;
    }
}

// ---------------- transpose-convert: src[K][N] fp32 -> dst[N][K] bf16 ----------------
__global__ void transpose_f32_bf16(const float* __restrict__ src, u16* __restrict__ dst,
                                   int K, int N) {
    __shared__ float tile[32][33];
    int n0 = blockIdx.x * 32, k0 = blockIdx.y * 32;
    int tx = threadIdx.x, ty = threadIdx.y;
#pragma unroll
    for (int i = 0; i < 32; i += 8)
        tile[ty + i][tx] = src[(size_t)(k0 + ty + i) * N + n0 + tx];
    __syncthreads();
#pragma unroll
    for (int i = 0; i < 32; i += 8)
        dst[(size_t)(n0 + ty + i) * K + k0 + tx] = f2bf(tile[tx][ty + i]);
}

// ---------------- fused qkv bias ----------------
__global__ void build_bias(const float* __restrict__ bq, const float* __restrict__ bk,
                           const float* __restrict__ bv, float* __restrict__ bqkv) {
    int i = blockIdx.x * 256 + threadIdx.x;
    if (i < QKV_N)
        bqkv[i] = (i < 2048) ? bq[i] : ((i < 2560) ? bk[i - 2048] : bv[i - 2560]);
}

// ---------------- pack attention_mask to bits: mp[b*32 + w] bit j = am[b*2048+w*64+j] ----
__global__ void pack_mask(const int* __restrict__ am, u64* __restrict__ mp) {
    int i = blockIdx.x * 64 + threadIdx.x;   // word index, 64 total
    if (i < BATCH * SEQ / 64) {
        const int* a = am + i * 64;
        u64 m = 0;
#pragma unroll
        for (int j = 0; j < 64; j += 4) {
            int4 v = *(const int4*)(a + j);
            m |= ((u64)(v.x != 0) << j) | ((u64)(v.y != 0) << (j + 1)) |
                 ((u64)(v.z != 0) << (j + 2)) | ((u64)(v.w != 0) << (j + 3));
        }
        mp[i] = m;
    }
}

// ---------------- V^T extraction from qkv buffer ----------------
// qkv row stride 3072; v at col 2560 + kvh*128 + d. VT layout: [b][kvh][d=128][s=2048]
__global__ void vt_from_qkv(const u16* __restrict__ qkv, u16* __restrict__ vt) {
    __shared__ u16 tile[32][33];
    int b = blockIdx.z >> 2, kvh = blockIdx.z & 3;
    int s0 = blockIdx.x * 32, d0 = blockIdx.y * 32;
    int tx = threadIdx.x, ty = threadIdx.y;
#pragma unroll
    for (int i = 0; i < 32; i += 8)
        tile[ty + i][tx] = qkv[(size_t)(b * SEQ + s0 + ty + i) * QKV_N + 2560 + kvh * HD + d0 + tx];
    __syncthreads();
#pragma unroll
    for (int i = 0; i < 32; i += 8)
        vt[(size_t)((b * NKV + kvh) * HD + d0 + ty + i) * SEQ + s0 + tx] = tile[tx][ty + i];
}

// ---------------- bf16 GEMM (m97 structure): out[M][N] = A[M][K] @ BT[N][K]^T + bias ----
// 128x128 tile, BK=32, 256 threads = 4 waves in 2x2; each wave 64x64 via 4x4 acc.
template <bool OUT_BF16>
__global__ __launch_bounds__(256)
void gemm_bf16_128(const u16* __restrict__ A, const u16* __restrict__ BT,
                   const float* __restrict__ bias, void* __restrict__ outp,
                   int M, int N, int K) {
    __shared__ __align__(16) u16 As[128][32];   // no pad: global_load_lds needs contiguous
    __shared__ __align__(16) u16 Bs[128][32];
    int t = threadIdx.x, w = t >> 6, lane = t & 63, quad = lane >> 4, l16 = lane & 15;
    int wm = w & 1, wn = w >> 1;
    int bm0 = blockIdx.y * 128, bn0 = blockIdx.x * 128;

    f32x4 acc[4][4];
#pragma unroll
    for (int i = 0; i < 4; i++)
#pragma unroll
        for (int j = 0; j < 4; j++) acc[i][j] = (f32x4){0.f, 0.f, 0.f, 0.f};

    for (int k0 = 0; k0 < K; k0 += 32) {
        __syncthreads();  // previous iter's LDS reads done
#pragma unroll
        for (int j = 0; j < 2; j++) {
            int f = (w * 2 + j) * 64 + lane;      // 0..511 (16B chunks)
            int row = f >> 2, col = (f & 3) * 8;  // 4 chunks of 8 bf16 per 32-col row
            u16* abase = &As[0][0] + (size_t)(w * 2 + j) * 512;  // wave-uniform
            u16* bbase = &Bs[0][0] + (size_t)(w * 2 + j) * 512;
            async_copy16(A + (size_t)(bm0 + row) * K + k0 + col, abase);
            async_copy16(BT + (size_t)(bn0 + row) * K + k0 + col, bbase);
        }
        __syncthreads();  // compiler drains vmcnt before barrier
        short8 af[4], bf[4];
#pragma unroll
        for (int mt = 0; mt < 4; mt++) af[mt] = *(const short8*)(&As[wm * 64 + mt * 16 + l16][quad * 8]);
#pragma unroll
        for (int nt = 0; nt < 4; nt++) bf[nt] = *(const short8*)(&Bs[wn * 64 + nt * 16 + l16][quad * 8]);
#pragma unroll
        for (int mt = 0; mt < 4; mt++)
#pragma unroll
            for (int nt = 0; nt < 4; nt++)
                acc[mt][nt] = __builtin_amdgcn_mfma_f32_16x16x32_bf16(af[mt], bf[nt], acc[mt][nt], 0, 0, 0);
    }
#pragma unroll
    for (int nt = 0; nt < 4; nt++) {
        int col = bn0 + wn * 64 + nt * 16 + l16;
        float bcol = bias[col];
#pragma unroll
        for (int mt = 0; mt < 4; mt++) {
#pragma unroll
            for (int r = 0; r < 4; r++) {
                int row = bm0 + wm * 64 + mt * 16 + quad * 4 + r;
                float v = acc[mt][nt][r] + bcol;
                if constexpr (OUT_BF16)
                    ((u16*)outp)[(size_t)row * N + col] = f2bf(v);
                else
                    ((float*)outp)[(size_t)row * N + col] = v;
            }
        }
    }
}

// ---------------- flash attention (causal, GQA), fixed-shift softmax --------
// grid (S/128, NH, BATCH), 512 threads = 8 waves; wave w owns q rows qt*128+w*16..+15.
// qt = bz ? G-1-bx : bx -> blocks id, id+256 (same CU, all co-resident) have
// complementary causal work. 2 blocks/CU (35.8 KB LDS each, VGPR<=128).
// Swapped QK^T (mfma(kf,qf) -> S^T): lane (quad,l16) holds, per key-tile nt,
// S[key=kb+nt*16+quad*4+r][qrow=q_row0+l16] -- a lane's 16 P values all belong
// to q-row l16. PV A-fragment built IN-REGISTER via cvt_pk + permlane swaps
// (T12); no P LDS round-trip, no lgkmcnt drain.
// Fixed-shift softmax: p = exp2(s*scale2 - C2); shift-invariant after the
// epilogue 1/l scaling; no in-loop cross-lane ops.
__global__ __launch_bounds__(512, 4)
void flash_attn(const u16* __restrict__ qkv, const u16* __restrict__ vt,
                const u64* __restrict__ mp, u16* __restrict__ attn) {
    __shared__ __align__(16) u16 Ks[64][136];   // 128 + 8 pad (natural key order)
    __shared__ __align__(16) u16 Vs[128][72];   // 64 + 8 pad
    int t = threadIdx.x, w = t >> 6, lane = t & 63, quad = lane >> 4, l16 = lane & 15;
    int bx = blockIdx.x, b = blockIdx.z;
    int qt = b ? ((int)gridDim.x - 1 - bx) : bx;    // complementary pairing
    int h = blockIdx.y, kvh = h >> 2;
    int q_row0 = qt * 128 + w * 16;

    // Q fragments: rows q_row0+l16, K-dim chunks of 32 (B-operand of swapped QK)
    const u16* qrow = qkv + (size_t)(b * SEQ + q_row0 + l16) * QKV_N + h * HD;
    short8 qf[4];
#pragma unroll
    for (int c = 0; c < 4; c++) qf[c] = *(const short8*)(qrow + c * 32 + quad * 8);

    f32x4 o[8];
#pragma unroll
    for (int dt = 0; dt < 8; dt++) o[dt] = (f32x4){0.f, 0.f, 0.f, 0.f};
    float lpart = 0.f;   // per-lane partial row-sum for q-row l16

    // exp(score*scale - 10) == exp2(score*scale2 - C2); ratio to l is shift-invariant.
    const float scale2 = 0.12751743f;   // (1/sqrt(128)) * log2(e)
    const float C2 = 14.4269504f;       // 10 * log2(e)

    const u16* kgb = qkv + (size_t)(b * SEQ) * QKV_N + 2048 + kvh * HD;
    const u16* vgb = vt + (size_t)((b * NKV + kvh) * HD) * SEQ;
    const u64* mpb = mp + b * (SEQ / 64);

    // staging: K tile 64x128 = 1024 16B-chunks; V tile 128x64 = 1024 chunks.
    // thread t handles K rows {kr, kr+32}, V rows {vr, vr+64}.
    int kr = t >> 4, kc = (t & 15) * 8;   // K: 16 chunks per 128-col row
    int vr = t >> 3, vc = (t & 7) * 8;    // V: 8 chunks per 64-col row
    int kb_end = (qt + 1) * 128;

    short8 k0p, k1p, v0p, v1p;
    {
        k0p = *(const short8*)(kgb + (size_t)kr * QKV_N + kc);
        k1p = *(const short8*)(kgb + (size_t)(kr + 32) * QKV_N + kc);
        v0p = *(const short8*)(vgb + (size_t)vr * SEQ + vc);
        v1p = *(const short8*)(vgb + (size_t)(vr + 64) * SEQ + vc);
    }

    for (int kb = 0; kb < kb_end; kb += 64) {
        __syncthreads();  // previous iter's LDS reads done
        *(short8*)(&Ks[kr][kc]) = k0p;
        *(short8*)(&Ks[kr + 32][kc]) = k1p;
        *(short8*)(&Vs[vr][vc]) = v0p;
        *(short8*)(&Vs[vr + 64][vc]) = v1p;
        __syncthreads();
        if (kb + 64 < kb_end) {  // prefetch next tile during compute (T14 issue-early)
            const u16* kg = kgb + (size_t)(kb + 64) * QKV_N;
            const u16* vg = vgb + kb + 64;
            k0p = *(const short8*)(kg + (size_t)kr * QKV_N + kc);
            k1p = *(const short8*)(kg + (size_t)(kr + 32) * QKV_N + kc);
            v0p = *(const short8*)(vg + (size_t)vr * SEQ + vc);
            v1p = *(const short8*)(vg + (size_t)(vr + 64) * SEQ + vc);
        }
        if (kb > q_row0 + 15) continue;  // wave-uniform: no keys for this wave's rows

        u64 mk = mpb[kb >> 6];   // wave-uniform mask bits for keys kb..kb+63

        // ---- scores (swapped): sc[nt][r] = S[key=kb+nt*16+quad*4+r][qrow=l16]
        f32x4 sc[4];
#pragma unroll
        for (int nt = 0; nt < 4; nt++) sc[nt] = (f32x4){0.f, 0.f, 0.f, 0.f};
        __builtin_amdgcn_s_setprio(1);
#pragma unroll
        for (int c = 0; c < 4; c++) {
#pragma unroll
            for (int nt = 0; nt < 4; nt++) {
                short8 kf = *(const short8*)(&Ks[nt * 16 + l16][c * 32 + quad * 8]);
                sc[nt] = __builtin_amdgcn_mfma_f32_16x16x32_bf16(kf, qf[c], sc[nt], 0, 0, 0);
            }
        }
        __builtin_amdgcn_s_setprio(0);

        // early V fragments (keys 0..31, dims 0..63): independent of softmax
        short8 vf0a[4];
#pragma unroll
        for (int dt = 0; dt < 4; dt++)
            vf0a[dt] = *(const short8*)(&Vs[dt * 16 + l16][quad * 8]);

        // ---- mask + fixed-shift exp; lane's keys: bp = nt*16+quad*4+r (+kb)
        int limit = q_row0 + l16 - kb;   // keep iff bp <= limit (causal)
        float p[4][4];
#pragma unroll
        for (int nt = 0; nt < 4; nt++) {
            unsigned nib = (unsigned)(mk >> (nt * 16 + quad * 4));
#pragma unroll
            for (int r = 0; r < 4; r++) {
                int bp = nt * 16 + quad * 4 + r;
                bool ok = ((nib >> r) & 1u) && (bp <= limit);
                float v = ok ? sc[nt][r] : -INFINITY;
                p[nt][r] = __builtin_exp2f(__builtin_fmaf(v, scale2, -C2));
            }
        }
        lpart += ((p[0][0] + p[0][1]) + (p[0][2] + p[0][3])) +
                 ((p[1][0] + p[1][1]) + (p[1][2] + p[1][3])) +
                 ((p[2][0] + p[2][1]) + (p[2][2] + p[2][3])) +
                 ((p[3][0] + p[3][1]) + (p[3][2] + p[3][3]));

        // ---- T12: pack to bf16 and redistribute quads in-register.
        // tile nt, lane quad q holds keys nt*16+4q..+3 -> packed dwords:
        //   X0|q = keys(nt*16+4q, +1), X1|q = keys(nt*16+4q+2, +3)
        // target A-frag pf (lane quad qt): keys base+8qt..+7 as dwords D0..D3.
        // (D0,D2) = p16swap(p32swap(A0,B0)); (D1,D3) = p16swap(p32swap(A1,B1)).
        unsigned A0, A1, B0, B1, C0, C1, E0, E1;
        asm("v_cvt_pk_bf16_f32 %0, %1, %2" : "=v"(A0) : "v"(p[0][0]), "v"(p[0][1]));
        asm("v_cvt_pk_bf16_f32 %0, %1, %2" : "=v"(A1) : "v"(p[0][2]), "v"(p[0][3]));
        asm("v_cvt_pk_bf16_f32 %0, %1, %2" : "=v"(B0) : "v"(p[1][0]), "v"(p[1][1]));
        asm("v_cvt_pk_bf16_f32 %0, %1, %2" : "=v"(B1) : "v"(p[1][2]), "v"(p[1][3]));
        asm("v_cvt_pk_bf16_f32 %0, %1, %2" : "=v"(C0) : "v"(p[2][0]), "v"(p[2][1]));
        asm("v_cvt_pk_bf16_f32 %0, %1, %2" : "=v"(C1) : "v"(p[2][2]), "v"(p[2][3]));
        asm("v_cvt_pk_bf16_f32 %0, %1, %2" : "=v"(E0) : "v"(p[3][0]), "v"(p[3][1]));
        asm("v_cvt_pk_bf16_f32 %0, %1, %2" : "=v"(E1) : "v"(p[3][2]), "v"(p[3][3]));
        // pf0 (keys 0..31) from tiles 0,1
        asm("v_permlane32_swap_b32 %0, %1" : "+v"(A0), "+v"(B0));
        asm("v_permlane16_swap_b32 %0, %1" : "+v"(A0), "+v"(B0));  // A0=D0, B0=D2
        asm("v_permlane32_swap_b32 %0, %1" : "+v"(A1), "+v"(B1));
        asm("v_permlane16_swap_b32 %0, %1" : "+v"(A1), "+v"(B1));  // A1=D1, B1=D3
        // pf1 (keys 32..63) from tiles 2,3
        asm("v_permlane32_swap_b32 %0, %1" : "+v"(C0), "+v"(E0));
        asm("v_permlane16_swap_b32 %0, %1" : "+v"(C0), "+v"(E0));
        asm("v_permlane32_swap_b32 %0, %1" : "+v"(C1), "+v"(E1));
        asm("v_permlane16_swap_b32 %0, %1" : "+v"(C1), "+v"(E1));
        short8 pf0 = __builtin_bit_cast(short8, (uint4v){A0, A1, B0, B1});
        short8 pf1 = __builtin_bit_cast(short8, (uint4v){C0, C1, E0, E1});

        __builtin_amdgcn_s_setprio(1);
#pragma unroll
        for (int dt = 0; dt < 4; dt++)
            o[dt] = __builtin_amdgcn_mfma_f32_16x16x32_bf16(pf0, vf0a[dt], o[dt], 0, 0, 0);
#pragma unroll
        for (int dt = 4; dt < 8; dt++) {
            short8 vf0 = *(const short8*)(&Vs[dt * 16 + l16][quad * 8]);
            o[dt] = __builtin_amdgcn_mfma_f32_16x16x32_bf16(pf0, vf0, o[dt], 0, 0, 0);
        }
#pragma unroll
        for (int dt = 0; dt < 8; dt++) {
            short8 vf1 = *(const short8*)(&Vs[dt * 16 + l16][32 + quad * 8]);
            o[dt] = __builtin_amdgcn_mfma_f32_16x16x32_bf16(pf1, vf1, o[dt], 0, 0, 0);
        }
        __builtin_amdgcn_s_setprio(0);
    }
    // epilogue: full row-sum for q-row l16, then redistribute to output rows.
    float l = lpart;
    l += __shfl_xor(l, 16, 64);
    l += __shfl_xor(l, 32, 64);   // every lane: sum for q-row l16
    float invq[4];
#pragma unroll
    for (int r = 0; r < 4; r++) {
        float lr = __shfl(l, quad * 4 + r, 16);   // sum for q-row quad*4+r
        invq[r] = lr > 0.f ? 1.f / lr : 0.f;
    }
    size_t obase = (size_t)(b * SEQ + q_row0) * HIDDEN + h * HD;
#pragma unroll
    for (int dt = 0; dt < 8; dt++)
#pragma unroll
        for (int r = 0; r < 4; r++)
            attn[obase + (size_t)(quad * 4 + r) * HIDDEN + dt * 16 + l16] =
                f2bf(o[dt][r] * invq[r]);
}

extern "C" void kernel_launch(void* const* d_in, const int* in_sizes, int n_in,
                              void* d_out, int out_size, void* d_ws, size_t ws_size,
                              hipStream_t stream) {
    const float* hidden = (const float*)d_in[0];
    const int* amask   = (const int*)d_in[1];
    const float* Wq = (const float*)d_in[2];
    const float* bq = (const float*)d_in[3];
    const float* Wk = (const float*)d_in[4];
    const float* bk = (const float*)d_in[5];
    const float* Wv = (const float*)d_in[6];
    const float* bv = (const float*)d_in[7];
    const float* Wo = (const float*)d_in[8];
    const float* bo = (const float*)d_in[9];
    float* out = (float*)d_out;

    // workspace layout (~84 MB)
    char* ws = (char*)d_ws;
    u16* xb     = (u16*)ws;  ws += (size_t)MROWS * HIDDEN * 2;        // 16.8 MB
    u16* wqkvT  = (u16*)ws;  ws += (size_t)QKV_N * HIDDEN * 2;       // 12.6 MB
    u16* woT    = (u16*)ws;  ws += (size_t)HIDDEN * HIDDEN * 2;      // 8.4 MB
    float* bqkv = (float*)ws; ws += (size_t)QKV_N * 4;               // 12 KB
    u64* mpk    = (u64*)ws;  ws += (size_t)(MROWS / 64) * 8;         // 512 B
    u16* qkv    = (u16*)ws;  ws += (size_t)MROWS * QKV_N * 2;        // 25.2 MB
    u16* vt     = (u16*)ws;  ws += (size_t)BATCH * NKV * HD * SEQ * 2; // 4.2 MB
    u16* attn   = (u16*)ws;  ws += (size_t)MROWS * HIDDEN * 2;       // 16.8 MB

    // 1. converts
    convert_f32_bf16<<<dim3(MROWS * HIDDEN / 1024), dim3(256), 0, stream>>>(hidden, xb, MROWS * HIDDEN);
    transpose_f32_bf16<<<dim3(64, 64), dim3(32, 8), 0, stream>>>(Wq, wqkvT, HIDDEN, 2048);
    transpose_f32_bf16<<<dim3(16, 64), dim3(32, 8), 0, stream>>>(Wk, wqkvT + (size_t)2048 * HIDDEN, HIDDEN, 512);
    transpose_f32_bf16<<<dim3(16, 64), dim3(32, 8), 0, stream>>>(Wv, wqkvT + (size_t)2560 * HIDDEN, HIDDEN, 512);
    transpose_f32_bf16<<<dim3(64, 64), dim3(32, 8), 0, stream>>>(Wo, woT, HIDDEN, HIDDEN);
    build_bias<<<dim3(12), dim3(256), 0, stream>>>(bq, bk, bv, bqkv);
    pack_mask<<<dim3(1), dim3(64), 0, stream>>>(amask, mpk);

    // 2. fused QKV projection (128x128 tile)
    gemm_bf16_128<true><<<dim3(QKV_N / 128, MROWS / 128), dim3(256), 0, stream>>>(
        xb, wqkvT, bqkv, qkv, MROWS, QKV_N, HIDDEN);

    // 3. V^T
    vt_from_qkv<<<dim3(SEQ / 32, HD / 32, BATCH * NKV), dim3(32, 8), 0, stream>>>(qkv, vt);

    // 4. attention (128 q rows per block, 8 waves x 16 rows, complementary pairing)
    flash_attn<<<dim3(SEQ / 128, NH, BATCH), dim3(512), 0, stream>>>(qkv, vt, mpk, attn);

    // 5. output projection (fp32 out)
    gemm_bf16_128<false><<<dim3(HIDDEN / 128, MROWS / 128), dim3(256), 0, stream>>>(
        attn, woT, bo, out, MROWS, HIDDEN, HIDDEN);
}

// Round 4
// 318.034 us; speedup vs baseline: 1.0866x; 1.0342x over previous
//
#include <hip/hip_runtime.h>
#include <hip/hip_bf16.h>

// CausalSelfAttention on MI355X (gfx950).
// B=2, S=2048, HIDDEN=2048, H=16 heads, D=128, Hkv=4 (GQA groups=4).
// Round 12: dispatch-count reduction. R11 accounting: total 328.9, flash 78.5,
//   GEMMs < 78.5 each (not in top-5) -> ~100 us of the budget is launch/gap
//   overhead across 11 dispatches (~10 us each, cf. rocprof.md). Fuse the 7
//   small prep kernels (convert, 4 transposes, build_bias, pack_mask) into ONE
//   `prep` kernel via 1-D grid block-range dispatch; sub-tasks keep their exact
//   former geometry. Kernel count 11 -> 5. flash_attn / GEMMs / vt_from_qkv
//   byte-identical to R11 (clean A/B on overhead).
//
// MFMA layouts (HW-verified per guide m89/m91/m120):
//   A frag: A[m=lane&15][k=(lane>>4)*8 + j], j=0..7  (16B contiguous in K)
//   B frag: B^T stored [n][k], same addressing as A
//   C/D   : col=lane&15, row=(lane>>4)*4 + reg

typedef unsigned short u16;
typedef unsigned long long u64;
typedef __attribute__((ext_vector_type(8))) short short8;   // 8 x bf16 (4 VGPRs)
typedef __attribute__((ext_vector_type(4))) float f32x4;
typedef __attribute__((ext_vector_type(4))) unsigned uint4v;

#define BATCH 2
#define SEQ 2048
#define HIDDEN 2048
#define NH 16
#define NKV 4
#define HD 128
#define QKV_N 3072   // 2048 q + 512 k + 512 v
#define MROWS 4096   // BATCH*SEQ

__device__ inline u16 f2bf(float f) {
    __hip_bfloat16 h = __float2bfloat16(f);
    return __builtin_bit_cast(u16, h);
}

// async global->LDS, 16B per lane; lds base must be wave-uniform (HW adds lane*16)
__device__ inline void async_copy16(const u16* g, u16* lds_base) {
    __builtin_amdgcn_global_load_lds(
        (const __attribute__((address_space(1))) void*)g,
        (__attribute__((address_space(3))) void*)lds_base, 16, 0, 0);
}

// ---------------- fused prep: convert + 4 transposes + bias + mask ----------------
// grid segments (256 threads each):
//   [0, 8192)            convert hidden fp32 -> xb bf16 (float4/thread)
//   [8192, 12288)        transpose Wq  (2048x2048) -> wqkvT[0..]
//   [12288, 13312)       transpose Wk  (2048x512)  -> wqkvT + 2048*2048
//   [13312, 14336)       transpose Wv  (2048x512)  -> wqkvT + 2560*2048
//   [14336, 18432)       transpose Wo  (2048x2048) -> woT
//   [18432, 18444)       build bqkv (12 blocks)
//   [18444]              pack mask bits (1 block, 64 lanes active)
#define PREP_CONV   8192
#define PREP_WQ     (PREP_CONV + 4096)
#define PREP_WK     (PREP_WQ + 1024)
#define PREP_WV     (PREP_WK + 1024)
#define PREP_WO     (PREP_WV + 4096)
#define PREP_BIAS   (PREP_WO + 12)
#define PREP_TOTAL  (PREP_BIAS + 1)

__device__ inline void prep_transpose(const float* __restrict__ src, u16* __restrict__ dst,
                                      int N, int sub, float (*tile)[33]) {
    // src[K=2048][N] fp32 -> dst[N][K] bf16; sub-blocks laid out x-major (N/32 wide)
    int nx = N >> 5;
    int bx = sub % nx, by = sub / nx;
    int n0 = bx * 32, k0 = by * 32;
    int t = threadIdx.x, tx = t & 31, ty = t >> 5;
#pragma unroll
    for (int i = 0; i < 32; i += 8)
        tile[ty + i][tx] = src[(size_t)(k0 + ty + i) * N + n0 + tx];
    __syncthreads();
#pragma unroll
    for (int i = 0; i < 32; i += 8)
        dst[(size_t)(n0 + ty + i) * HIDDEN + k0 + tx] = f2bf(tile[tx][ty + i]);
}

__global__ __launch_bounds__(256)
void prep(const float* __restrict__ hidden, u16* __restrict__ xb,
          const float* __restrict__ Wq, const float* __restrict__ Wk,
          const float* __restrict__ Wv, const float* __restrict__ Wo,
          u16* __restrict__ wqkvT, u16* __restrict__ woT,
          const float* __restrict__ bq, const float* __restrict__ bk,
          const float* __restrict__ bv, float* __restrict__ bqkv,
          const int* __restrict__ am, u64* __restrict__ mp) {
    __shared__ float tile[32][33];
    int bid = blockIdx.x;
    if (bid < PREP_CONV) {
        int i = (bid * 256 + threadIdx.x) * 4;
        float4 v = *(const float4*)(hidden + i);
        ushort4 o;
        o.x = f2bf(v.x); o.y = f2bf(v.y); o.z = f2bf(v.z); o.w = f2bf(v.w);
        *(ushort4*)(xb + i) = o;
    } else if (bid < PREP_WQ) {
        prep_transpose(Wq, wqkvT, 2048, bid - PREP_CONV, tile);
    } else if (bid < PREP_WK) {
        prep_transpose(Wk, wqkvT + (size_t)2048 * HIDDEN, 512, bid - PREP_WQ, tile);
    } else if (bid < PREP_WV) {
        prep_transpose(Wv, wqkvT + (size_t)2560 * HIDDEN, 512, bid - PREP_WK, tile);
    } else if (bid < PREP_WO) {
        prep_transpose(Wo, woT, 2048, bid - PREP_WV, tile);
    } else if (bid < PREP_BIAS) {
        int i = (bid - PREP_WO) * 256 + threadIdx.x;
        if (i < QKV_N)
            bqkv[i] = (i < 2048) ? bq[i] : ((i < 2560) ? bk[i - 2048] : bv[i - 2560]);
    } else {
        int i = threadIdx.x;   // word index, 64 total
        if (i < BATCH * SEQ / 64) {
            const int* a = am + i * 64;
            u64 m = 0;
#pragma unroll
            for (int j = 0; j < 64; j += 4) {
                int4 v = *(const int4*)(a + j);
                m |= ((u64)(v.x != 0) << j) | ((u64)(v.y != 0) << (j + 1)) |
                     ((u64)(v.z != 0) << (j + 2)) | ((u64)(v.w != 0) << (j + 3));
            }
            mp[i] = m;
        }
    }
}

// ---------------- V^T extraction from qkv buffer ----------------
// qkv row stride 3072; v at col 2560 + kvh*128 + d. VT layout: [b][kvh][d=128][s=2048]
__global__ void vt_from_qkv(const u16* __restrict__ qkv, u16* __restrict__ vt) {
    __shared__ u16 tile[32][33];
    int b = blockIdx.z >> 2, kvh = blockIdx.z & 3;
    int s0 = blockIdx.x * 32, d0 = blockIdx.y * 32;
    int tx = threadIdx.x, ty = threadIdx.y;
#pragma unroll
    for (int i = 0; i < 32; i += 8)
        tile[ty + i][tx] = qkv[(size_t)(b * SEQ + s0 + ty + i) * QKV_N + 2560 + kvh * HD + d0 + tx];
    __syncthreads();
#pragma unroll
    for (int i = 0; i < 32; i += 8)
        vt[(size_t)((b * NKV + kvh) * HD + d0 + ty + i) * SEQ + s0 + tx] = tile[tx][ty + i];
}

// ---------------- bf16 GEMM (m97 structure): out[M][N] = A[M][K] @ BT[N][K]^T + bias ----
// 128x128 tile, BK=32, 256 threads = 4 waves in 2x2; each wave 64x64 via 4x4 acc.
template <bool OUT_BF16>
__global__ __launch_bounds__(256)
void gemm_bf16_128(const u16* __restrict__ A, const u16* __restrict__ BT,
                   const float* __restrict__ bias, void* __restrict__ outp,
                   int M, int N, int K) {
    __shared__ __align__(16) u16 As[128][32];   // no pad: global_load_lds needs contiguous
    __shared__ __align__(16) u16 Bs[128][32];
    int t = threadIdx.x, w = t >> 6, lane = t & 63, quad = lane >> 4, l16 = lane & 15;
    int wm = w & 1, wn = w >> 1;
    int bm0 = blockIdx.y * 128, bn0 = blockIdx.x * 128;

    f32x4 acc[4][4];
#pragma unroll
    for (int i = 0; i < 4; i++)
#pragma unroll
        for (int j = 0; j < 4; j++) acc[i][j] = (f32x4){0.f, 0.f, 0.f, 0.f};

    for (int k0 = 0; k0 < K; k0 += 32) {
        __syncthreads();  // previous iter's LDS reads done
#pragma unroll
        for (int j = 0; j < 2; j++) {
            int f = (w * 2 + j) * 64 + lane;      // 0..511 (16B chunks)
            int row = f >> 2, col = (f & 3) * 8;  // 4 chunks of 8 bf16 per 32-col row
            u16* abase = &As[0][0] + (size_t)(w * 2 + j) * 512;  // wave-uniform
            u16* bbase = &Bs[0][0] + (size_t)(w * 2 + j) * 512;
            async_copy16(A + (size_t)(bm0 + row) * K + k0 + col, abase);
            async_copy16(BT + (size_t)(bn0 + row) * K + k0 + col, bbase);
        }
        __syncthreads();  // compiler drains vmcnt before barrier
        short8 af[4], bf[4];
#pragma unroll
        for (int mt = 0; mt < 4; mt++) af[mt] = *(const short8*)(&As[wm * 64 + mt * 16 + l16][quad * 8]);
#pragma unroll
        for (int nt = 0; nt < 4; nt++) bf[nt] = *(const short8*)(&Bs[wn * 64 + nt * 16 + l16][quad * 8]);
#pragma unroll
        for (int mt = 0; mt < 4; mt++)
#pragma unroll
            for (int nt = 0; nt < 4; nt++)
                acc[mt][nt] = __builtin_amdgcn_mfma_f32_16x16x32_bf16(af[mt], bf[nt], acc[mt][nt], 0, 0, 0);
    }
#pragma unroll
    for (int nt = 0; nt < 4; nt++) {
        int col = bn0 + wn * 64 + nt * 16 + l16;
        float bcol = bias[col];
#pragma unroll
        for (int mt = 0; mt < 4; mt++) {
#pragma unroll
            for (int r = 0; r < 4; r++) {
                int row = bm0 + wm * 64 + mt * 16 + quad * 4 + r;
                float v = acc[mt][nt][r] + bcol;
                if constexpr (OUT_BF16)
                    ((u16*)outp)[(size_t)row * N + col] = f2bf(v);
                else
                    ((float*)outp)[(size_t)row * N + col] = v;
            }
        }
    }
}

// ---------------- flash attention (causal, GQA), fixed-shift softmax --------
// grid (S/128, NH, BATCH), 512 threads = 8 waves; wave w owns q rows qt*128+w*16..+15.
// qt = bz ? G-1-bx : bx -> blocks id, id+256 (same CU, all co-resident) have
// complementary causal work. 2 blocks/CU (35.8 KB LDS each, VGPR<=128).
// Swapped QK^T (mfma(kf,qf) -> S^T): lane (quad,l16) holds, per key-tile nt,
// S[key=kb+nt*16+quad*4+r][qrow=q_row0+l16] -- a lane's 16 P values all belong
// to q-row l16. PV A-fragment built IN-REGISTER via cvt_pk + permlane swaps
// (T12); no P LDS round-trip, no lgkmcnt drain.
// Fixed-shift softmax: p = exp2(s*scale2 - C2); shift-invariant after the
// epilogue 1/l scaling; no in-loop cross-lane ops.
__global__ __launch_bounds__(512, 4)
void flash_attn(const u16* __restrict__ qkv, const u16* __restrict__ vt,
                const u64* __restrict__ mp, u16* __restrict__ attn) {
    __shared__ __align__(16) u16 Ks[64][136];   // 128 + 8 pad (natural key order)
    __shared__ __align__(16) u16 Vs[128][72];   // 64 + 8 pad
    int t = threadIdx.x, w = t >> 6, lane = t & 63, quad = lane >> 4, l16 = lane & 15;
    int bx = blockIdx.x, b = blockIdx.z;
    int qt = b ? ((int)gridDim.x - 1 - bx) : bx;    // complementary pairing
    int h = blockIdx.y, kvh = h >> 2;
    int q_row0 = qt * 128 + w * 16;

    // Q fragments: rows q_row0+l16, K-dim chunks of 32 (B-operand of swapped QK)
    const u16* qrow = qkv + (size_t)(b * SEQ + q_row0 + l16) * QKV_N + h * HD;
    short8 qf[4];
#pragma unroll
    for (int c = 0; c < 4; c++) qf[c] = *(const short8*)(qrow + c * 32 + quad * 8);

    f32x4 o[8];
#pragma unroll
    for (int dt = 0; dt < 8; dt++) o[dt] = (f32x4){0.f, 0.f, 0.f, 0.f};
    float lpart = 0.f;   // per-lane partial row-sum for q-row l16

    // exp(score*scale - 10) == exp2(score*scale2 - C2); ratio to l is shift-invariant.
    const float scale2 = 0.12751743f;   // (1/sqrt(128)) * log2(e)
    const float C2 = 14.4269504f;       // 10 * log2(e)

    const u16* kgb = qkv + (size_t)(b * SEQ) * QKV_N + 2048 + kvh * HD;
    const u16* vgb = vt + (size_t)((b * NKV + kvh) * HD) * SEQ;
    const u64* mpb = mp + b * (SEQ / 64);

    // staging: K tile 64x128 = 1024 16B-chunks; V tile 128x64 = 1024 chunks.
    // thread t handles K rows {kr, kr+32}, V rows {vr, vr+64}.
    int kr = t >> 4, kc = (t & 15) * 8;   // K: 16 chunks per 128-col row
    int vr = t >> 3, vc = (t & 7) * 8;    // V: 8 chunks per 64-col row
    int kb_end = (qt + 1) * 128;

    short8 k0p, k1p, v0p, v1p;
    {
        k0p = *(const short8*)(kgb + (size_t)kr * QKV_N + kc);
        k1p = *(const short8*)(kgb + (size_t)(kr + 32) * QKV_N + kc);
        v0p = *(const short8*)(vgb + (size_t)vr * SEQ + vc);
        v1p = *(const short8*)(vgb + (size_t)(vr + 64) * SEQ + vc);
    }

    for (int kb = 0; kb < kb_end; kb += 64) {
        __syncthreads();  // previous iter's LDS reads done
        *(short8*)(&Ks[kr][kc]) = k0p;
        *(short8*)(&Ks[kr + 32][kc]) = k1p;
        *(short8*)(&Vs[vr][vc]) = v0p;
        *(short8*)(&Vs[vr + 64][vc]) = v1p;
        __syncthreads();
        if (kb + 64 < kb_end) {  // prefetch next tile during compute (T14 issue-early)
            const u16* kg = kgb + (size_t)(kb + 64) * QKV_N;
            const u16* vg = vgb + kb + 64;
            k0p = *(const short8*)(kg + (size_t)kr * QKV_N + kc);
            k1p = *(const short8*)(kg + (size_t)(kr + 32) * QKV_N + kc);
            v0p = *(const short8*)(vg + (size_t)vr * SEQ + vc);
            v1p = *(const short8*)(vg + (size_t)(vr + 64) * SEQ + vc);
        }
        if (kb > q_row0 + 15) continue;  // wave-uniform: no keys for this wave's rows

        u64 mk = mpb[kb >> 6];   // wave-uniform mask bits for keys kb..kb+63

        // ---- scores (swapped): sc[nt][r] = S[key=kb+nt*16+quad*4+r][qrow=l16]
        f32x4 sc[4];
#pragma unroll
        for (int nt = 0; nt < 4; nt++) sc[nt] = (f32x4){0.f, 0.f, 0.f, 0.f};
        __builtin_amdgcn_s_setprio(1);
#pragma unroll
        for (int c = 0; c < 4; c++) {
#pragma unroll
            for (int nt = 0; nt < 4; nt++) {
                short8 kf = *(const short8*)(&Ks[nt * 16 + l16][c * 32 + quad * 8]);
                sc[nt] = __builtin_amdgcn_mfma_f32_16x16x32_bf16(kf, qf[c], sc[nt], 0, 0, 0);
            }
        }
        __builtin_amdgcn_s_setprio(0);

        // early V fragments (keys 0..31, dims 0..63): independent of softmax
        short8 vf0a[4];
#pragma unroll
        for (int dt = 0; dt < 4; dt++)
            vf0a[dt] = *(const short8*)(&Vs[dt * 16 + l16][quad * 8]);

        // ---- mask + fixed-shift exp; lane's keys: bp = nt*16+quad*4+r (+kb)
        int limit = q_row0 + l16 - kb;   // keep iff bp <= limit (causal)
        float p[4][4];
#pragma unroll
        for (int nt = 0; nt < 4; nt++) {
            unsigned nib = (unsigned)(mk >> (nt * 16 + quad * 4));
#pragma unroll
            for (int r = 0; r < 4; r++) {
                int bp = nt * 16 + quad * 4 + r;
                bool ok = ((nib >> r) & 1u) && (bp <= limit);
                float v = ok ? sc[nt][r] : -INFINITY;
                p[nt][r] = __builtin_exp2f(__builtin_fmaf(v, scale2, -C2));
            }
        }
        lpart += ((p[0][0] + p[0][1]) + (p[0][2] + p[0][3])) +
                 ((p[1][0] + p[1][1]) + (p[1][2] + p[1][3])) +
                 ((p[2][0] + p[2][1]) + (p[2][2] + p[2][3])) +
                 ((p[3][0] + p[3][1]) + (p[3][2] + p[3][3]));

        // ---- T12: pack to bf16 and redistribute quads in-register.
        // tile nt, lane quad q holds keys nt*16+4q..+3 -> packed dwords:
        //   X0|q = keys(nt*16+4q, +1), X1|q = keys(nt*16+4q+2, +3)
        // target A-frag pf (lane quad qt): keys base+8qt..+7 as dwords D0..D3.
        // (D0,D2) = p16swap(p32swap(A0,B0)); (D1,D3) = p16swap(p32swap(A1,B1)).
        unsigned A0, A1, B0, B1, C0, C1, E0, E1;
        asm("v_cvt_pk_bf16_f32 %0, %1, %2" : "=v"(A0) : "v"(p[0][0]), "v"(p[0][1]));
        asm("v_cvt_pk_bf16_f32 %0, %1, %2" : "=v"(A1) : "v"(p[0][2]), "v"(p[0][3]));
        asm("v_cvt_pk_bf16_f32 %0, %1, %2" : "=v"(B0) : "v"(p[1][0]), "v"(p[1][1]));
        asm("v_cvt_pk_bf16_f32 %0, %1, %2" : "=v"(B1) : "v"(p[1][2]), "v"(p[1][3]));
        asm("v_cvt_pk_bf16_f32 %0, %1, %2" : "=v"(C0) : "v"(p[2][0]), "v"(p[2][1]));
        asm("v_cvt_pk_bf16_f32 %0, %1, %2" : "=v"(C1) : "v"(p[2][2]), "v"(p[2][3]));
        asm("v_cvt_pk_bf16_f32 %0, %1, %2" : "=v"(E0) : "v"(p[3][0]), "v"(p[3][1]));
        asm("v_cvt_pk_bf16_f32 %0, %1, %2" : "=v"(E1) : "v"(p[3][2]), "v"(p[3][3]));
        // pf0 (keys 0..31) from tiles 0,1
        asm("v_permlane32_swap_b32 %0, %1" : "+v"(A0), "+v"(B0));
        asm("v_permlane16_swap_b32 %0, %1" : "+v"(A0), "+v"(B0));  // A0=D0, B0=D2
        asm("v_permlane32_swap_b32 %0, %1" : "+v"(A1), "+v"(B1));
        asm("v_permlane16_swap_b32 %0, %1" : "+v"(A1), "+v"(B1));  // A1=D1, B1=D3
        // pf1 (keys 32..63) from tiles 2,3
        asm("v_permlane32_swap_b32 %0, %1" : "+v"(C0), "+v"(E0));
        asm("v_permlane16_swap_b32 %0, %1" : "+v"(C0), "+v"(E0));
        asm("v_permlane32_swap_b32 %0, %1" : "+v"(C1), "+v"(E1));
        asm("v_permlane16_swap_b32 %0, %1" : "+v"(C1), "+v"(E1));
        short8 pf0 = __builtin_bit_cast(short8, (uint4v){A0, A1, B0, B1});
        short8 pf1 = __builtin_bit_cast(short8, (uint4v){C0, C1, E0, E1});

        __builtin_amdgcn_s_setprio(1);
#pragma unroll
        for (int dt = 0; dt < 4; dt++)
            o[dt] = __builtin_amdgcn_mfma_f32_16x16x32_bf16(pf0, vf0a[dt], o[dt], 0, 0, 0);
#pragma unroll
        for (int dt = 4; dt < 8; dt++) {
            short8 vf0 = *(const short8*)(&Vs[dt * 16 + l16][quad * 8]);
            o[dt] = __builtin_amdgcn_mfma_f32_16x16x32_bf16(pf0, vf0, o[dt], 0, 0, 0);
        }
#pragma unroll
        for (int dt = 0; dt < 8; dt++) {
            short8 vf1 = *(const short8*)(&Vs[dt * 16 + l16][32 + quad * 8]);
            o[dt] = __builtin_amdgcn_mfma_f32_16x16x32_bf16(pf1, vf1, o[dt], 0, 0, 0);
        }
        __builtin_amdgcn_s_setprio(0);
    }
    // epilogue: full row-sum for q-row l16, then redistribute to output rows.
    float l = lpart;
    l += __shfl_xor(l, 16, 64);
    l += __shfl_xor(l, 32, 64);   // every lane: sum for q-row l16
    float invq[4];
#pragma unroll
    for (int r = 0; r < 4; r++) {
        float lr = __shfl(l, quad * 4 + r, 16);   // sum for q-row quad*4+r
        invq[r] = lr > 0.f ? 1.f / lr : 0.f;
    }
    size_t obase = (size_t)(b * SEQ + q_row0) * HIDDEN + h * HD;
#pragma unroll
    for (int dt = 0; dt < 8; dt++)
#pragma unroll
        for (int r = 0; r < 4; r++)
            attn[obase + (size_t)(quad * 4 + r) * HIDDEN + dt * 16 + l16] =
                f2bf(o[dt][r] * invq[r]);
}

extern "C" void kernel_launch(void* const* d_in, const int* in_sizes, int n_in,
                              void* d_out, int out_size, void* d_ws, size_t ws_size,
                              hipStream_t stream) {
    const float* hidden = (const float*)d_in[0];
    const int* amask   = (const int*)d_in[1];
    const float* Wq = (const float*)d_in[2];
    const float* bq = (const float*)d_in[3];
    const float* Wk = (const float*)d_in[4];
    const float* bk = (const float*)d_in[5];
    const float* Wv = (const float*)d_in[6];
    const float* bv = (const float*)d_in[7];
    const float* Wo = (const float*)d_in[8];
    const float* bo = (const float*)d_in[9];
    float* out = (float*)d_out;

    // workspace layout (~84 MB)
    char* ws = (char*)d_ws;
    u16* xb     = (u16*)ws;  ws += (size_t)MROWS * HIDDEN * 2;        // 16.8 MB
    u16* wqkvT  = (u16*)ws;  ws += (size_t)QKV_N * HIDDEN * 2;       // 12.6 MB
    u16* woT    = (u16*)ws;  ws += (size_t)HIDDEN * HIDDEN * 2;      // 8.4 MB
    float* bqkv = (float*)ws; ws += (size_t)QKV_N * 4;               // 12 KB
    u64* mpk    = (u64*)ws;  ws += (size_t)(MROWS / 64) * 8;         // 512 B
    u16* qkv    = (u16*)ws;  ws += (size_t)MROWS * QKV_N * 2;        // 25.2 MB
    u16* vt     = (u16*)ws;  ws += (size_t)BATCH * NKV * HD * SEQ * 2; // 4.2 MB
    u16* attn   = (u16*)ws;  ws += (size_t)MROWS * HIDDEN * 2;       // 16.8 MB

    // 1. fused prep (convert + 4 transposes + bias + mask) -- one dispatch
    prep<<<dim3(PREP_TOTAL), dim3(256), 0, stream>>>(
        hidden, xb, Wq, Wk, Wv, Wo, wqkvT, woT, bq, bk, bv, bqkv, amask, mpk);

    // 2. fused QKV projection (128x128 tile)
    gemm_bf16_128<true><<<dim3(QKV_N / 128, MROWS / 128), dim3(256), 0, stream>>>(
        xb, wqkvT, bqkv, qkv, MROWS, QKV_N, HIDDEN);

    // 3. V^T
    vt_from_qkv<<<dim3(SEQ / 32, HD / 32, BATCH * NKV), dim3(32, 8), 0, stream>>>(qkv, vt);

    // 4. attention (128 q rows per block, 8 waves x 16 rows, complementary pairing)
    flash_attn<<<dim3(SEQ / 128, NH, BATCH), dim3(512), 0, stream>>>(qkv, vt, mpk, attn);

    // 5. output projection (fp32 out)
    gemm_bf16_128<false><<<dim3(HIDDEN / 128, MROWS / 128), dim3(256), 0, stream>>>(
        attn, woT, bo, out, MROWS, HIDDEN, HIDDEN);
}

// Round 5
// 298.539 us; speedup vs baseline: 1.1576x; 1.0653x over previous
//
#include <hip/hip_runtime.h>
#include <hip/hip_bf16.h>

// CausalSelfAttention on MI355X (gfx950).
// B=2, S=2048, HIDDEN=2048, H=16 heads, D=128, Hkv=4 (GQA groups=4).
// Round 13: 256^2 8-phase counted-vmcnt GEMM (T2+T3+T4+T5) replacing the m97
//   2-phase 128^2 GEMM for BOTH projections. R12 A/B: dispatch gaps ~1.8us ->
//   GEMMs are ~70-78 + ~50-58 us (each just under flash's 78.6, hence absent
//   from top-5). The m97 structure is at its ceiling; the 8-phase template is
//   the proven 1.7x lever.
//   Design (ledger-verified): BM=BN=256 BK=64, 512thr 8 waves (2Mx4N), dbuf
//   LDS 128KB, interleaved frag tiling so each phase-quadrant consumes one
//   128-row half-tile; 4 phases/tile (12/4/8/0 ds_read_b128 + 16 MFMA); stage
//   1 half-tile/phase in order Ah0,Bh0,Bh1,Ah1; phase tails vmcnt(4)+s_barrier
//   (ph2: vmcnt(6)); single vmcnt(0) at peeled last tile. T2 swizzle:
//   chunk ^= row&7 on BOTH global source (linear gload_lds dest) and ds_read.
//   setprio(1) around MFMA clusters. Raw s_barrier (no __syncthreads drain).
//   flash_attn / prep / vt_from_qkv byte-identical to R12.
//
// MFMA layouts (HW-verified per guide m89/m91/m120):
//   A frag: A[m=lane&15][k=(lane>>4)*8 + j], j=0..7  (16B contiguous in K)
//   B frag: B^T stored [n][k], same addressing as A
//   C/D   : col=lane&15, row=(lane>>4)*4 + reg

typedef unsigned short u16;
typedef unsigned long long u64;
typedef __attribute__((ext_vector_type(8))) short short8;   // 8 x bf16 (4 VGPRs)
typedef __attribute__((ext_vector_type(4))) float f32x4;
typedef __attribute__((ext_vector_type(4))) unsigned uint4v;

#define BATCH 2
#define SEQ 2048
#define HIDDEN 2048
#define NH 16
#define NKV 4
#define HD 128
#define QKV_N 3072   // 2048 q + 512 k + 512 v
#define MROWS 4096   // BATCH*SEQ

__device__ inline u16 f2bf(float f) {
    __hip_bfloat16 h = __float2bfloat16(f);
    return __builtin_bit_cast(u16, h);
}

// async global->LDS, 16B per lane; lds base must be wave-uniform (HW adds lane*16)
__device__ inline void async_copy16(const u16* g, u16* lds_base) {
    __builtin_amdgcn_global_load_lds(
        (const __attribute__((address_space(1))) void*)g,
        (__attribute__((address_space(3))) void*)lds_base, 16, 0, 0);
}

// ---------------- fused prep: convert + 4 transposes + bias + mask ----------------
#define PREP_CONV   8192
#define PREP_WQ     (PREP_CONV + 4096)
#define PREP_WK     (PREP_WQ + 1024)
#define PREP_WV     (PREP_WK + 1024)
#define PREP_WO     (PREP_WV + 4096)
#define PREP_BIAS   (PREP_WO + 12)
#define PREP_TOTAL  (PREP_BIAS + 1)

__device__ inline void prep_transpose(const float* __restrict__ src, u16* __restrict__ dst,
                                      int N, int sub, float (*tile)[33]) {
    int nx = N >> 5;
    int bx = sub % nx, by = sub / nx;
    int n0 = bx * 32, k0 = by * 32;
    int t = threadIdx.x, tx = t & 31, ty = t >> 5;
#pragma unroll
    for (int i = 0; i < 32; i += 8)
        tile[ty + i][tx] = src[(size_t)(k0 + ty + i) * N + n0 + tx];
    __syncthreads();
#pragma unroll
    for (int i = 0; i < 32; i += 8)
        dst[(size_t)(n0 + ty + i) * HIDDEN + k0 + tx] = f2bf(tile[tx][ty + i]);
}

__global__ __launch_bounds__(256)
void prep(const float* __restrict__ hidden, u16* __restrict__ xb,
          const float* __restrict__ Wq, const float* __restrict__ Wk,
          const float* __restrict__ Wv, const float* __restrict__ Wo,
          u16* __restrict__ wqkvT, u16* __restrict__ woT,
          const float* __restrict__ bq, const float* __restrict__ bk,
          const float* __restrict__ bv, float* __restrict__ bqkv,
          const int* __restrict__ am, u64* __restrict__ mp) {
    __shared__ float tile[32][33];
    int bid = blockIdx.x;
    if (bid < PREP_CONV) {
        int i = (bid * 256 + threadIdx.x) * 4;
        float4 v = *(const float4*)(hidden + i);
        ushort4 o;
        o.x = f2bf(v.x); o.y = f2bf(v.y); o.z = f2bf(v.z); o.w = f2bf(v.w);
        *(ushort4*)(xb + i) = o;
    } else if (bid < PREP_WQ) {
        prep_transpose(Wq, wqkvT, 2048, bid - PREP_CONV, tile);
    } else if (bid < PREP_WK) {
        prep_transpose(Wk, wqkvT + (size_t)2048 * HIDDEN, 512, bid - PREP_WQ, tile);
    } else if (bid < PREP_WV) {
        prep_transpose(Wv, wqkvT + (size_t)2560 * HIDDEN, 512, bid - PREP_WK, tile);
    } else if (bid < PREP_WO) {
        prep_transpose(Wo, woT, 2048, bid - PREP_WV, tile);
    } else if (bid < PREP_BIAS) {
        int i = (bid - PREP_WO) * 256 + threadIdx.x;
        if (i < QKV_N)
            bqkv[i] = (i < 2048) ? bq[i] : ((i < 2560) ? bk[i - 2048] : bv[i - 2560]);
    } else {
        int i = threadIdx.x;   // word index, 64 total
        if (i < BATCH * SEQ / 64) {
            const int* a = am + i * 64;
            u64 m = 0;
#pragma unroll
            for (int j = 0; j < 64; j += 4) {
                int4 v = *(const int4*)(a + j);
                m |= ((u64)(v.x != 0) << j) | ((u64)(v.y != 0) << (j + 1)) |
                     ((u64)(v.z != 0) << (j + 2)) | ((u64)(v.w != 0) << (j + 3));
            }
            mp[i] = m;
        }
    }
}

// ---------------- V^T extraction from qkv buffer ----------------
__global__ void vt_from_qkv(const u16* __restrict__ qkv, u16* __restrict__ vt) {
    __shared__ u16 tile[32][33];
    int b = blockIdx.z >> 2, kvh = blockIdx.z & 3;
    int s0 = blockIdx.x * 32, d0 = blockIdx.y * 32;
    int tx = threadIdx.x, ty = threadIdx.y;
#pragma unroll
    for (int i = 0; i < 32; i += 8)
        tile[ty + i][tx] = qkv[(size_t)(b * SEQ + s0 + ty + i) * QKV_N + 2560 + kvh * HD + d0 + tx];
    __syncthreads();
#pragma unroll
    for (int i = 0; i < 32; i += 8)
        vt[(size_t)((b * NKV + kvh) * HD + d0 + ty + i) * SEQ + s0 + tx] = tile[tx][ty + i];
}

// ---------------- bf16 GEMM, 256^2 8-phase counted-vmcnt (T2+T3+T4+T5) ----------
// out[M][N] = A[M][K] @ BT[N][K]^T + bias.  BM=BN=256, BK=64, 512 thr = 8 waves
// (2M x 4N). Interleaved frag tiling: A-row = mt*32+wm*16+l16 (mt 0..7),
// B-row = nt*64+wn*16+l16 (nt 0..3) -> each phase-quadrant consumes exactly one
// 128-row half-tile. LDS [buf][op][256][64] double-buffered = 128 KiB, 1 blk/CU.
// T2 swizzle: 16B-chunk index ^= (row&7) on BOTH the global source (linear
// global_load_lds dest) and the ds_read -> even 8-bank-group spread.
// Phases per K-tile t (snake (0,0)(0,1)(1,1)(1,0)); stage half-tiles of t+1 in
// order Ah0,Bh0,Bh1,Ah1; tails vmcnt(4)+s_barrier (ph2: vmcnt(6)).
// Ledger (per wave, 2 instr per half-tile): entering ph0 outstanding =
// [Bh1(t),Ah1(t)]=4; ph0 +Ah0(t+1) -> vmcnt(4) completes Bh1(t) (ph1's reads);
// ph1 +Bh0(t+1) -> vmcnt(4) completes Ah1(t) (ph2's reads); ph2 +Bh1(t+1) ->
// vmcnt(6) no-wait; ph3 +Ah1(t+1)=8 -> vmcnt(4) completes Ah0,Bh0(t+1) (next
// ph0). Prologue stages tile0 then vmcnt(4)+barrier; peeled last tile after a
// single vmcnt(0)+barrier, no further syncs.
template <bool OUT_BF16>
__global__ __launch_bounds__(512, 2)
void gemm_bf16_256(const u16* __restrict__ A, const u16* __restrict__ BT,
                   const float* __restrict__ bias, void* __restrict__ outp,
                   int M, int N, int K) {
    __shared__ __align__(16) u16 smem[2][2][256][64];   // [buf][A=0/B=1][row][col] 128 KiB
    const int t = threadIdx.x, w = t >> 6, lane = t & 63;
    const int quad = lane >> 4, l16 = lane & 15;
    const int wm = w >> 2, wn = w & 3;
    const int bm0 = blockIdx.y * 256, bn0 = blockIdx.x * 256;
    const int lrow = lane >> 3;            // staging: row within 8-row group
    const int lchk = (lane & 7) ^ lrow;    // staging: swizzled source chunk
    const int NT = K >> 6;

    f32x4 acc[8][4];
#pragma unroll
    for (int i = 0; i < 8; i++)
#pragma unroll
        for (int j = 0; j < 4; j++) acc[i][j] = (f32x4){0.f, 0.f, 0.f, 0.f};

    const u16* gA = A + (size_t)bm0 * K;
    const u16* gB = BT + (size_t)bn0 * K;

    // stage one half-tile (128 rows x 64 cols) of operand op into buf at k0.
    auto stage = [&](int buf, int op, int h, int k0) {
        const u16* gb = op ? gB : gA;
#pragma unroll
        for (int l = 0; l < 2; ++l) {
            int rb = h * 128 + w * 16 + l * 8;             // wave-uniform row base
            async_copy16(gb + (size_t)(rb + lrow) * K + k0 + lchk * 8,
                         &smem[buf][op][rb][0]);
        }
    };
    auto readA = [&](short8 (&aq)[4][2], int buf, int mh) {
#pragma unroll
        for (int mt = 0; mt < 4; ++mt) {
            int row = mh * 128 + mt * 32 + wm * 16 + l16;
            int swz = row & 7;
#pragma unroll
            for (int kk = 0; kk < 2; ++kk) {
                int chunk = ((kk << 2) | quad) ^ swz;
                aq[mt][kk] = *(const short8*)(&smem[buf][0][row][chunk << 3]);
            }
        }
    };
    auto readB = [&](short8 (&bq)[2][2], int buf, int nh) {
#pragma unroll
        for (int nt = 0; nt < 2; ++nt) {
            int row = nh * 128 + nt * 64 + wn * 16 + l16;
            int swz = row & 7;
#pragma unroll
            for (int kk = 0; kk < 2; ++kk) {
                int chunk = ((kk << 2) | quad) ^ swz;
                bq[nt][kk] = *(const short8*)(&smem[buf][1][row][chunk << 3]);
            }
        }
    };
    auto mmaQ = [&](short8 (&aq)[4][2], short8 (&bq)[2][2], int mh, int nh) {
        __builtin_amdgcn_s_setprio(1);
#pragma unroll
        for (int mt = 0; mt < 4; ++mt)
#pragma unroll
            for (int nt = 0; nt < 2; ++nt)
#pragma unroll
                for (int kk = 0; kk < 2; ++kk)
                    acc[mh * 4 + mt][nh * 2 + nt] = __builtin_amdgcn_mfma_f32_16x16x32_bf16(
                        aq[mt][kk], bq[nt][kk], acc[mh * 4 + mt][nh * 2 + nt], 0, 0, 0);
        __builtin_amdgcn_s_setprio(0);
    };

    // prologue: stage tile 0 -> buf 0 in order Ah0, Bh0, Bh1, Ah1
    stage(0, 0, 0, 0); stage(0, 1, 0, 0); stage(0, 1, 1, 0); stage(0, 0, 1, 0);
    asm volatile("s_waitcnt vmcnt(4)" ::: "memory");
    __builtin_amdgcn_s_barrier();

    short8 aq[4][2], b0[2][2], b1[2][2];
    for (int tt = 0; tt < NT - 1; ++tt) {
        const int cur = tt & 1, nxt = cur ^ 1, k1 = (tt + 1) << 6;
        // ph0: quadrant (0,0)
        readA(aq, cur, 0); readB(b0, cur, 0);
        stage(nxt, 0, 0, k1);                  // Ah0(t+1)
        mmaQ(aq, b0, 0, 0);
        asm volatile("s_waitcnt vmcnt(4)" ::: "memory");
        __builtin_amdgcn_s_barrier();
        // ph1: quadrant (0,1)
        readB(b1, cur, 1);
        stage(nxt, 1, 0, k1);                  // Bh0(t+1)
        mmaQ(aq, b1, 0, 1);
        asm volatile("s_waitcnt vmcnt(4)" ::: "memory");
        __builtin_amdgcn_s_barrier();
        // ph2: quadrant (1,1)
        readA(aq, cur, 1);
        stage(nxt, 1, 1, k1);                  // Bh1(t+1)
        mmaQ(aq, b1, 1, 1);
        asm volatile("s_waitcnt vmcnt(6)" ::: "memory");
        __builtin_amdgcn_s_barrier();
        // ph3: quadrant (1,0)
        stage(nxt, 0, 1, k1);                  // Ah1(t+1)
        mmaQ(aq, b0, 1, 0);
        asm volatile("s_waitcnt vmcnt(4)" ::: "memory");
        __builtin_amdgcn_s_barrier();
    }
    // peeled last tile: everything landed; no staging, no further barriers
    asm volatile("s_waitcnt vmcnt(0)" ::: "memory");
    __builtin_amdgcn_s_barrier();
    {
        const int cur = (NT - 1) & 1;
        readA(aq, cur, 0); readB(b0, cur, 0);
        mmaQ(aq, b0, 0, 0);
        readB(b1, cur, 1);
        mmaQ(aq, b1, 0, 1);
        readA(aq, cur, 1);
        mmaQ(aq, b1, 1, 1);
        mmaQ(aq, b0, 1, 0);
    }

    // epilogue
#pragma unroll
    for (int nt = 0; nt < 4; ++nt) {
        int col = bn0 + nt * 64 + wn * 16 + l16;
        float bcol = bias[col];
#pragma unroll
        for (int mt = 0; mt < 8; ++mt) {
#pragma unroll
            for (int r = 0; r < 4; ++r) {
                int row = bm0 + mt * 32 + wm * 16 + quad * 4 + r;
                float v = acc[mt][nt][r] + bcol;
                if constexpr (OUT_BF16)
                    ((u16*)outp)[(size_t)row * N + col] = f2bf(v);
                else
                    ((float*)outp)[(size_t)row * N + col] = v;
            }
        }
    }
}

// ---------------- flash attention (causal, GQA), fixed-shift softmax --------
// (byte-identical to R12)
__global__ __launch_bounds__(512, 4)
void flash_attn(const u16* __restrict__ qkv, const u16* __restrict__ vt,
                const u64* __restrict__ mp, u16* __restrict__ attn) {
    __shared__ __align__(16) u16 Ks[64][136];   // 128 + 8 pad (natural key order)
    __shared__ __align__(16) u16 Vs[128][72];   // 64 + 8 pad
    int t = threadIdx.x, w = t >> 6, lane = t & 63, quad = lane >> 4, l16 = lane & 15;
    int bx = blockIdx.x, b = blockIdx.z;
    int qt = b ? ((int)gridDim.x - 1 - bx) : bx;    // complementary pairing
    int h = blockIdx.y, kvh = h >> 2;
    int q_row0 = qt * 128 + w * 16;

    const u16* qrow = qkv + (size_t)(b * SEQ + q_row0 + l16) * QKV_N + h * HD;
    short8 qf[4];
#pragma unroll
    for (int c = 0; c < 4; c++) qf[c] = *(const short8*)(qrow + c * 32 + quad * 8);

    f32x4 o[8];
#pragma unroll
    for (int dt = 0; dt < 8; dt++) o[dt] = (f32x4){0.f, 0.f, 0.f, 0.f};
    float lpart = 0.f;   // per-lane partial row-sum for q-row l16

    const float scale2 = 0.12751743f;   // (1/sqrt(128)) * log2(e)
    const float C2 = 14.4269504f;       // 10 * log2(e)

    const u16* kgb = qkv + (size_t)(b * SEQ) * QKV_N + 2048 + kvh * HD;
    const u16* vgb = vt + (size_t)((b * NKV + kvh) * HD) * SEQ;
    const u64* mpb = mp + b * (SEQ / 64);

    int kr = t >> 4, kc = (t & 15) * 8;   // K: 16 chunks per 128-col row
    int vr = t >> 3, vc = (t & 7) * 8;    // V: 8 chunks per 64-col row
    int kb_end = (qt + 1) * 128;

    short8 k0p, k1p, v0p, v1p;
    {
        k0p = *(const short8*)(kgb + (size_t)kr * QKV_N + kc);
        k1p = *(const short8*)(kgb + (size_t)(kr + 32) * QKV_N + kc);
        v0p = *(const short8*)(vgb + (size_t)vr * SEQ + vc);
        v1p = *(const short8*)(vgb + (size_t)(vr + 64) * SEQ + vc);
    }

    for (int kb = 0; kb < kb_end; kb += 64) {
        __syncthreads();  // previous iter's LDS reads done
        *(short8*)(&Ks[kr][kc]) = k0p;
        *(short8*)(&Ks[kr + 32][kc]) = k1p;
        *(short8*)(&Vs[vr][vc]) = v0p;
        *(short8*)(&Vs[vr + 64][vc]) = v1p;
        __syncthreads();
        if (kb + 64 < kb_end) {  // prefetch next tile during compute (T14 issue-early)
            const u16* kg = kgb + (size_t)(kb + 64) * QKV_N;
            const u16* vg = vgb + kb + 64;
            k0p = *(const short8*)(kg + (size_t)kr * QKV_N + kc);
            k1p = *(const short8*)(kg + (size_t)(kr + 32) * QKV_N + kc);
            v0p = *(const short8*)(vg + (size_t)vr * SEQ + vc);
            v1p = *(const short8*)(vg + (size_t)(vr + 64) * SEQ + vc);
        }
        if (kb > q_row0 + 15) continue;  // wave-uniform: no keys for this wave's rows

        u64 mk = mpb[kb >> 6];   // wave-uniform mask bits for keys kb..kb+63

        // ---- scores (swapped): sc[nt][r] = S[key=kb+nt*16+quad*4+r][qrow=l16]
        f32x4 sc[4];
#pragma unroll
        for (int nt = 0; nt < 4; nt++) sc[nt] = (f32x4){0.f, 0.f, 0.f, 0.f};
        __builtin_amdgcn_s_setprio(1);
#pragma unroll
        for (int c = 0; c < 4; c++) {
#pragma unroll
            for (int nt = 0; nt < 4; nt++) {
                short8 kf = *(const short8*)(&Ks[nt * 16 + l16][c * 32 + quad * 8]);
                sc[nt] = __builtin_amdgcn_mfma_f32_16x16x32_bf16(kf, qf[c], sc[nt], 0, 0, 0);
            }
        }
        __builtin_amdgcn_s_setprio(0);

        // early V fragments (keys 0..31, dims 0..63): independent of softmax
        short8 vf0a[4];
#pragma unroll
        for (int dt = 0; dt < 4; dt++)
            vf0a[dt] = *(const short8*)(&Vs[dt * 16 + l16][quad * 8]);

        // ---- mask + fixed-shift exp; lane's keys: bp = nt*16+quad*4+r (+kb)
        int limit = q_row0 + l16 - kb;   // keep iff bp <= limit (causal)
        float p[4][4];
#pragma unroll
        for (int nt = 0; nt < 4; nt++) {
            unsigned nib = (unsigned)(mk >> (nt * 16 + quad * 4));
#pragma unroll
            for (int r = 0; r < 4; r++) {
                int bp = nt * 16 + quad * 4 + r;
                bool ok = ((nib >> r) & 1u) && (bp <= limit);
                float v = ok ? sc[nt][r] : -INFINITY;
                p[nt][r] = __builtin_exp2f(__builtin_fmaf(v, scale2, -C2));
            }
        }
        lpart += ((p[0][0] + p[0][1]) + (p[0][2] + p[0][3])) +
                 ((p[1][0] + p[1][1]) + (p[1][2] + p[1][3])) +
                 ((p[2][0] + p[2][1]) + (p[2][2] + p[2][3])) +
                 ((p[3][0] + p[3][1]) + (p[3][2] + p[3][3]));

        // ---- T12: pack to bf16 and redistribute quads in-register.
        unsigned A0, A1, B0, B1, C0, C1, E0, E1;
        asm("v_cvt_pk_bf16_f32 %0, %1, %2" : "=v"(A0) : "v"(p[0][0]), "v"(p[0][1]));
        asm("v_cvt_pk_bf16_f32 %0, %1, %2" : "=v"(A1) : "v"(p[0][2]), "v"(p[0][3]));
        asm("v_cvt_pk_bf16_f32 %0, %1, %2" : "=v"(B0) : "v"(p[1][0]), "v"(p[1][1]));
        asm("v_cvt_pk_bf16_f32 %0, %1, %2" : "=v"(B1) : "v"(p[1][2]), "v"(p[1][3]));
        asm("v_cvt_pk_bf16_f32 %0, %1, %2" : "=v"(C0) : "v"(p[2][0]), "v"(p[2][1]));
        asm("v_cvt_pk_bf16_f32 %0, %1, %2" : "=v"(C1) : "v"(p[2][2]), "v"(p[2][3]));
        asm("v_cvt_pk_bf16_f32 %0, %1, %2" : "=v"(E0) : "v"(p[3][0]), "v"(p[3][1]));
        asm("v_cvt_pk_bf16_f32 %0, %1, %2" : "=v"(E1) : "v"(p[3][2]), "v"(p[3][3]));
        asm("v_permlane32_swap_b32 %0, %1" : "+v"(A0), "+v"(B0));
        asm("v_permlane16_swap_b32 %0, %1" : "+v"(A0), "+v"(B0));  // A0=D0, B0=D2
        asm("v_permlane32_swap_b32 %0, %1" : "+v"(A1), "+v"(B1));
        asm("v_permlane16_swap_b32 %0, %1" : "+v"(A1), "+v"(B1));  // A1=D1, B1=D3
        asm("v_permlane32_swap_b32 %0, %1" : "+v"(C0), "+v"(E0));
        asm("v_permlane16_swap_b32 %0, %1" : "+v"(C0), "+v"(E0));
        asm("v_permlane32_swap_b32 %0, %1" : "+v"(C1), "+v"(E1));
        asm("v_permlane16_swap_b32 %0, %1" : "+v"(C1), "+v"(E1));
        short8 pf0 = __builtin_bit_cast(short8, (uint4v){A0, A1, B0, B1});
        short8 pf1 = __builtin_bit_cast(short8, (uint4v){C0, C1, E0, E1});

        __builtin_amdgcn_s_setprio(1);
#pragma unroll
        for (int dt = 0; dt < 4; dt++)
            o[dt] = __builtin_amdgcn_mfma_f32_16x16x32_bf16(pf0, vf0a[dt], o[dt], 0, 0, 0);
#pragma unroll
        for (int dt = 4; dt < 8; dt++) {
            short8 vf0 = *(const short8*)(&Vs[dt * 16 + l16][quad * 8]);
            o[dt] = __builtin_amdgcn_mfma_f32_16x16x32_bf16(pf0, vf0, o[dt], 0, 0, 0);
        }
#pragma unroll
        for (int dt = 0; dt < 8; dt++) {
            short8 vf1 = *(const short8*)(&Vs[dt * 16 + l16][32 + quad * 8]);
            o[dt] = __builtin_amdgcn_mfma_f32_16x16x32_bf16(pf1, vf1, o[dt], 0, 0, 0);
        }
        __builtin_amdgcn_s_setprio(0);
    }
    // epilogue: full row-sum for q-row l16, then redistribute to output rows.
    float l = lpart;
    l += __shfl_xor(l, 16, 64);
    l += __shfl_xor(l, 32, 64);   // every lane: sum for q-row l16
    float invq[4];
#pragma unroll
    for (int r = 0; r < 4; r++) {
        float lr = __shfl(l, quad * 4 + r, 16);   // sum for q-row quad*4+r
        invq[r] = lr > 0.f ? 1.f / lr : 0.f;
    }
    size_t obase = (size_t)(b * SEQ + q_row0) * HIDDEN + h * HD;
#pragma unroll
    for (int dt = 0; dt < 8; dt++)
#pragma unroll
        for (int r = 0; r < 4; r++)
            attn[obase + (size_t)(quad * 4 + r) * HIDDEN + dt * 16 + l16] =
                f2bf(o[dt][r] * invq[r]);
}

extern "C" void kernel_launch(void* const* d_in, const int* in_sizes, int n_in,
                              void* d_out, int out_size, void* d_ws, size_t ws_size,
                              hipStream_t stream) {
    const float* hidden = (const float*)d_in[0];
    const int* amask   = (const int*)d_in[1];
    const float* Wq = (const float*)d_in[2];
    const float* bq = (const float*)d_in[3];
    const float* Wk = (const float*)d_in[4];
    const float* bk = (const float*)d_in[5];
    const float* Wv = (const float*)d_in[6];
    const float* bv = (const float*)d_in[7];
    const float* Wo = (const float*)d_in[8];
    const float* bo = (const float*)d_in[9];
    float* out = (float*)d_out;

    // workspace layout (~84 MB)
    char* ws = (char*)d_ws;
    u16* xb     = (u16*)ws;  ws += (size_t)MROWS * HIDDEN * 2;        // 16.8 MB
    u16* wqkvT  = (u16*)ws;  ws += (size_t)QKV_N * HIDDEN * 2;       // 12.6 MB
    u16* woT    = (u16*)ws;  ws += (size_t)HIDDEN * HIDDEN * 2;      // 8.4 MB
    float* bqkv = (float*)ws; ws += (size_t)QKV_N * 4;               // 12 KB
    u64* mpk    = (u64*)ws;  ws += (size_t)(MROWS / 64) * 8;         // 512 B
    u16* qkv    = (u16*)ws;  ws += (size_t)MROWS * QKV_N * 2;        // 25.2 MB
    u16* vt     = (u16*)ws;  ws += (size_t)BATCH * NKV * HD * SEQ * 2; // 4.2 MB
    u16* attn   = (u16*)ws;  ws += (size_t)MROWS * HIDDEN * 2;       // 16.8 MB

    // 1. fused prep (convert + 4 transposes + bias + mask) -- one dispatch
    prep<<<dim3(PREP_TOTAL), dim3(256), 0, stream>>>(
        hidden, xb, Wq, Wk, Wv, Wo, wqkvT, woT, bq, bk, bv, bqkv, amask, mpk);

    // 2. fused QKV projection (256^2 8-phase)
    gemm_bf16_256<true><<<dim3(QKV_N / 256, MROWS / 256), dim3(512), 0, stream>>>(
        xb, wqkvT, bqkv, qkv, MROWS, QKV_N, HIDDEN);

    // 3. V^T
    vt_from_qkv<<<dim3(SEQ / 32, HD / 32, BATCH * NKV), dim3(32, 8), 0, stream>>>(qkv, vt);

    // 4. attention (128 q rows per block, 8 waves x 16 rows, complementary pairing)
    flash_attn<<<dim3(SEQ / 128, NH, BATCH), dim3(512), 0, stream>>>(qkv, vt, mpk, attn);

    // 5. output projection (256^2 8-phase, fp32 out)
    gemm_bf16_256<false><<<dim3(HIDDEN / 256, MROWS / 256), dim3(512), 0, stream>>>(
        attn, woT, bo, out, MROWS, HIDDEN, HIDDEN);
}

// Round 6
// 293.315 us; speedup vs baseline: 1.1782x; 1.0178x over previous
//
#include <hip/hip_runtime.h>
#include <hip/hip_bf16.h>

// CausalSelfAttention on MI355X (gfx950).
// B=2, S=2048, HIDDEN=2048, H=16 heads, D=128, Hkv=4 (GQA groups=4).
// Round 14: (a) prep transpose rewrite -- R13 bound analysis (top-5 cut 79.8us,
//   only flash present) proves prep ~60-75us vs ~25us BW ideal. Old transposes
//   used scalar 2B global stores (8x instr bloat). New: 64x64 tiles, float4
//   coalesced reads -> LDS tl[64][69] (both phases verified 2-way bank = free)
//   -> short8 16B coalesced stores; 2560 blocks vs 10240. Convert: 8/thread.
//   (b) flash softmax fast path: masking VALU (cmp+cndmask+bit-extract, ~40% of
//   in-loop VALU) skipped on fully-causal-valid tiles (mk==~0 && kb+63<=q_row0,
//   wave-uniform, ~85-90% of compute iters).
//   (c) GEMMs byte-identical to R13; once flash < ~73us the QKV GEMM surfaces
//   in top-5 with counters -> direct diagnosis next round.
//
// MFMA layouts (HW-verified per guide m89/m91/m120):
//   A frag: A[m=lane&15][k=(lane>>4)*8 + j], j=0..7  (16B contiguous in K)
//   B frag: B^T stored [n][k], same addressing as A
//   C/D   : col=lane&15, row=(lane>>4)*4 + reg

typedef unsigned short u16;
typedef unsigned long long u64;
typedef __attribute__((ext_vector_type(8))) short short8;   // 8 x bf16 (4 VGPRs)
typedef __attribute__((ext_vector_type(4))) float f32x4;
typedef __attribute__((ext_vector_type(4))) unsigned uint4v;

#define BATCH 2
#define SEQ 2048
#define HIDDEN 2048
#define NH 16
#define NKV 4
#define HD 128
#define QKV_N 3072   // 2048 q + 512 k + 512 v
#define MROWS 4096   // BATCH*SEQ

__device__ inline u16 f2bf(float f) {
    __hip_bfloat16 h = __float2bfloat16(f);
    return __builtin_bit_cast(u16, h);
}

// async global->LDS, 16B per lane; lds base must be wave-uniform (HW adds lane*16)
__device__ inline void async_copy16(const u16* g, u16* lds_base) {
    __builtin_amdgcn_global_load_lds(
        (const __attribute__((address_space(1))) void*)g,
        (__attribute__((address_space(3))) void*)lds_base, 16, 0, 0);
}

// ---------------- fused prep: convert + 4 transposes + bias + mask ----------------
// grid segments (256 threads each):
//   [0, 4096)        convert hidden fp32 -> xb bf16 (8 elems/thread, 16B store)
//   [..+1024)        transpose Wq  (2048x2048) -> wqkvT[0..]
//   [..+256)         transpose Wk  (2048x512)  -> wqkvT + 2048*2048
//   [..+256)         transpose Wv  (2048x512)  -> wqkvT + 2560*2048
//   [..+1024)        transpose Wo  (2048x2048) -> woT
//   [..+12)          build bqkv
//   [..+1]           pack mask bits
#define PREP_CONV   4096
#define PREP_WQ     (PREP_CONV + 1024)
#define PREP_WK     (PREP_WQ + 256)
#define PREP_WV     (PREP_WK + 256)
#define PREP_WO     (PREP_WV + 1024)
#define PREP_BIAS   (PREP_WO + 12)
#define PREP_TOTAL  (PREP_BIAS + 1)

// src[K=2048][N] fp32 -> dst[N][2048] bf16, one 64x64 tile per block.
// Read: float4 coalesced; LDS tl[n][k] (69-pad: write scatter and read both
// exactly 2-way bank = free); write: short8 16B stores, 64B/row-group coalesced.
__device__ inline void prep_transpose64(const float* __restrict__ src, u16* __restrict__ dst,
                                        int N, int sub, float (*tl)[69]) {
    int nx = N >> 6;
    int bx = sub % nx, by = sub / nx;
    int n0 = bx * 64, k0 = by * 64;
    int t = threadIdx.x;
    int rr = t >> 4, cc = (t & 15) * 4;       // read rows k0+rr+16j, cols n0+cc..+3
#pragma unroll
    for (int j = 0; j < 4; ++j) {
        float4 v = *(const float4*)(src + (size_t)(k0 + rr + 16 * j) * N + n0 + cc);
        int k = rr + 16 * j;
        tl[cc + 0][k] = v.x;
        tl[cc + 1][k] = v.y;
        tl[cc + 2][k] = v.z;
        tl[cc + 3][k] = v.w;
    }
    __syncthreads();
    int n = t >> 2;                            // write dst row n0+n, 2 chunks of 8 k
#pragma unroll
    for (int j = 0; j < 2; ++j) {
        int kk = (t & 3) * 8 + 32 * j;
        short8 o8;
#pragma unroll
        for (int i = 0; i < 8; ++i) o8[i] = (short)f2bf(tl[n][kk + i]);
        *(short8*)(dst + (size_t)(n0 + n) * HIDDEN + k0 + kk) = o8;
    }
}

__global__ __launch_bounds__(256)
void prep(const float* __restrict__ hidden, u16* __restrict__ xb,
          const float* __restrict__ Wq, const float* __restrict__ Wk,
          const float* __restrict__ Wv, const float* __restrict__ Wo,
          u16* __restrict__ wqkvT, u16* __restrict__ woT,
          const float* __restrict__ bq, const float* __restrict__ bk,
          const float* __restrict__ bv, float* __restrict__ bqkv,
          const int* __restrict__ am, u64* __restrict__ mp) {
    __shared__ float tl[64][69];
    int bid = blockIdx.x;
    if (bid < PREP_CONV) {
        int i = (bid * 256 + threadIdx.x) * 8;
        float4 v0 = *(const float4*)(hidden + i);
        float4 v1 = *(const float4*)(hidden + i + 4);
        short8 o8;
        o8[0] = (short)f2bf(v0.x); o8[1] = (short)f2bf(v0.y);
        o8[2] = (short)f2bf(v0.z); o8[3] = (short)f2bf(v0.w);
        o8[4] = (short)f2bf(v1.x); o8[5] = (short)f2bf(v1.y);
        o8[6] = (short)f2bf(v1.z); o8[7] = (short)f2bf(v1.w);
        *(short8*)(xb + i) = o8;
    } else if (bid < PREP_WQ) {
        prep_transpose64(Wq, wqkvT, 2048, bid - PREP_CONV, tl);
    } else if (bid < PREP_WK) {
        prep_transpose64(Wk, wqkvT + (size_t)2048 * HIDDEN, 512, bid - PREP_WQ, tl);
    } else if (bid < PREP_WV) {
        prep_transpose64(Wv, wqkvT + (size_t)2560 * HIDDEN, 512, bid - PREP_WK, tl);
    } else if (bid < PREP_WO) {
        prep_transpose64(Wo, woT, 2048, bid - PREP_WV, tl);
    } else if (bid < PREP_BIAS) {
        int i = (bid - PREP_WO) * 256 + threadIdx.x;
        if (i < QKV_N)
            bqkv[i] = (i < 2048) ? bq[i] : ((i < 2560) ? bk[i - 2048] : bv[i - 2560]);
    } else {
        int i = threadIdx.x;   // word index, 64 total
        if (i < BATCH * SEQ / 64) {
            const int* a = am + i * 64;
            u64 m = 0;
#pragma unroll
            for (int j = 0; j < 64; j += 4) {
                int4 v = *(const int4*)(a + j);
                m |= ((u64)(v.x != 0) << j) | ((u64)(v.y != 0) << (j + 1)) |
                     ((u64)(v.z != 0) << (j + 2)) | ((u64)(v.w != 0) << (j + 3));
            }
            mp[i] = m;
        }
    }
}

// ---------------- V^T extraction from qkv buffer ----------------
__global__ void vt_from_qkv(const u16* __restrict__ qkv, u16* __restrict__ vt) {
    __shared__ u16 tile[32][33];
    int b = blockIdx.z >> 2, kvh = blockIdx.z & 3;
    int s0 = blockIdx.x * 32, d0 = blockIdx.y * 32;
    int tx = threadIdx.x, ty = threadIdx.y;
#pragma unroll
    for (int i = 0; i < 32; i += 8)
        tile[ty + i][tx] = qkv[(size_t)(b * SEQ + s0 + ty + i) * QKV_N + 2560 + kvh * HD + d0 + tx];
    __syncthreads();
#pragma unroll
    for (int i = 0; i < 32; i += 8)
        vt[(size_t)((b * NKV + kvh) * HD + d0 + ty + i) * SEQ + s0 + tx] = tile[tx][ty + i];
}

// ---------------- bf16 GEMM, 256^2 8-phase counted-vmcnt (T2+T3+T4+T5) ----------
// (byte-identical to R13; see R13 ledger comments)
template <bool OUT_BF16>
__global__ __launch_bounds__(512, 2)
void gemm_bf16_256(const u16* __restrict__ A, const u16* __restrict__ BT,
                   const float* __restrict__ bias, void* __restrict__ outp,
                   int M, int N, int K) {
    __shared__ __align__(16) u16 smem[2][2][256][64];   // [buf][A=0/B=1][row][col] 128 KiB
    const int t = threadIdx.x, w = t >> 6, lane = t & 63;
    const int quad = lane >> 4, l16 = lane & 15;
    const int wm = w >> 2, wn = w & 3;
    const int bm0 = blockIdx.y * 256, bn0 = blockIdx.x * 256;
    const int lrow = lane >> 3;            // staging: row within 8-row group
    const int lchk = (lane & 7) ^ lrow;    // staging: swizzled source chunk
    const int NT = K >> 6;

    f32x4 acc[8][4];
#pragma unroll
    for (int i = 0; i < 8; i++)
#pragma unroll
        for (int j = 0; j < 4; j++) acc[i][j] = (f32x4){0.f, 0.f, 0.f, 0.f};

    const u16* gA = A + (size_t)bm0 * K;
    const u16* gB = BT + (size_t)bn0 * K;

    auto stage = [&](int buf, int op, int h, int k0) {
        const u16* gb = op ? gB : gA;
#pragma unroll
        for (int l = 0; l < 2; ++l) {
            int rb = h * 128 + w * 16 + l * 8;             // wave-uniform row base
            async_copy16(gb + (size_t)(rb + lrow) * K + k0 + lchk * 8,
                         &smem[buf][op][rb][0]);
        }
    };
    auto readA = [&](short8 (&aq)[4][2], int buf, int mh) {
#pragma unroll
        for (int mt = 0; mt < 4; ++mt) {
            int row = mh * 128 + mt * 32 + wm * 16 + l16;
            int swz = row & 7;
#pragma unroll
            for (int kk = 0; kk < 2; ++kk) {
                int chunk = ((kk << 2) | quad) ^ swz;
                aq[mt][kk] = *(const short8*)(&smem[buf][0][row][chunk << 3]);
            }
        }
    };
    auto readB = [&](short8 (&bq)[2][2], int buf, int nh) {
#pragma unroll
        for (int nt = 0; nt < 2; ++nt) {
            int row = nh * 128 + nt * 64 + wn * 16 + l16;
            int swz = row & 7;
#pragma unroll
            for (int kk = 0; kk < 2; ++kk) {
                int chunk = ((kk << 2) | quad) ^ swz;
                bq[nt][kk] = *(const short8*)(&smem[buf][1][row][chunk << 3]);
            }
        }
    };
    auto mmaQ = [&](short8 (&aq)[4][2], short8 (&bq)[2][2], int mh, int nh) {
        __builtin_amdgcn_s_setprio(1);
#pragma unroll
        for (int mt = 0; mt < 4; ++mt)
#pragma unroll
            for (int nt = 0; nt < 2; ++nt)
#pragma unroll
                for (int kk = 0; kk < 2; ++kk)
                    acc[mh * 4 + mt][nh * 2 + nt] = __builtin_amdgcn_mfma_f32_16x16x32_bf16(
                        aq[mt][kk], bq[nt][kk], acc[mh * 4 + mt][nh * 2 + nt], 0, 0, 0);
        __builtin_amdgcn_s_setprio(0);
    };

    // prologue: stage tile 0 -> buf 0 in order Ah0, Bh0, Bh1, Ah1
    stage(0, 0, 0, 0); stage(0, 1, 0, 0); stage(0, 1, 1, 0); stage(0, 0, 1, 0);
    asm volatile("s_waitcnt vmcnt(4)" ::: "memory");
    __builtin_amdgcn_s_barrier();

    short8 aq[4][2], b0[2][2], b1[2][2];
    for (int tt = 0; tt < NT - 1; ++tt) {
        const int cur = tt & 1, nxt = cur ^ 1, k1 = (tt + 1) << 6;
        // ph0: quadrant (0,0)
        readA(aq, cur, 0); readB(b0, cur, 0);
        stage(nxt, 0, 0, k1);                  // Ah0(t+1)
        mmaQ(aq, b0, 0, 0);
        asm volatile("s_waitcnt vmcnt(4)" ::: "memory");
        __builtin_amdgcn_s_barrier();
        // ph1: quadrant (0,1)
        readB(b1, cur, 1);
        stage(nxt, 1, 0, k1);                  // Bh0(t+1)
        mmaQ(aq, b1, 0, 1);
        asm volatile("s_waitcnt vmcnt(4)" ::: "memory");
        __builtin_amdgcn_s_barrier();
        // ph2: quadrant (1,1)
        readA(aq, cur, 1);
        stage(nxt, 1, 1, k1);                  // Bh1(t+1)
        mmaQ(aq, b1, 1, 1);
        asm volatile("s_waitcnt vmcnt(6)" ::: "memory");
        __builtin_amdgcn_s_barrier();
        // ph3: quadrant (1,0)
        stage(nxt, 0, 1, k1);                  // Ah1(t+1)
        mmaQ(aq, b0, 1, 0);
        asm volatile("s_waitcnt vmcnt(4)" ::: "memory");
        __builtin_amdgcn_s_barrier();
    }
    // peeled last tile
    asm volatile("s_waitcnt vmcnt(0)" ::: "memory");
    __builtin_amdgcn_s_barrier();
    {
        const int cur = (NT - 1) & 1;
        readA(aq, cur, 0); readB(b0, cur, 0);
        mmaQ(aq, b0, 0, 0);
        readB(b1, cur, 1);
        mmaQ(aq, b1, 0, 1);
        readA(aq, cur, 1);
        mmaQ(aq, b1, 1, 1);
        mmaQ(aq, b0, 1, 0);
    }

    // epilogue
#pragma unroll
    for (int nt = 0; nt < 4; ++nt) {
        int col = bn0 + nt * 64 + wn * 16 + l16;
        float bcol = bias[col];
#pragma unroll
        for (int mt = 0; mt < 8; ++mt) {
#pragma unroll
            for (int r = 0; r < 4; ++r) {
                int row = bm0 + mt * 32 + wm * 16 + quad * 4 + r;
                float v = acc[mt][nt][r] + bcol;
                if constexpr (OUT_BF16)
                    ((u16*)outp)[(size_t)row * N + col] = f2bf(v);
                else
                    ((float*)outp)[(size_t)row * N + col] = v;
            }
        }
    }
}

// ---------------- flash attention (causal, GQA), fixed-shift softmax --------
// R14: wave-uniform fast path skips masking VALU on fully-valid tiles.
__global__ __launch_bounds__(512, 4)
void flash_attn(const u16* __restrict__ qkv, const u16* __restrict__ vt,
                const u64* __restrict__ mp, u16* __restrict__ attn) {
    __shared__ __align__(16) u16 Ks[64][136];   // 128 + 8 pad (natural key order)
    __shared__ __align__(16) u16 Vs[128][72];   // 64 + 8 pad
    int t = threadIdx.x, w = t >> 6, lane = t & 63, quad = lane >> 4, l16 = lane & 15;
    int bx = blockIdx.x, b = blockIdx.z;
    int qt = b ? ((int)gridDim.x - 1 - bx) : bx;    // complementary pairing
    int h = blockIdx.y, kvh = h >> 2;
    int q_row0 = qt * 128 + w * 16;

    const u16* qrow = qkv + (size_t)(b * SEQ + q_row0 + l16) * QKV_N + h * HD;
    short8 qf[4];
#pragma unroll
    for (int c = 0; c < 4; c++) qf[c] = *(const short8*)(qrow + c * 32 + quad * 8);

    f32x4 o[8];
#pragma unroll
    for (int dt = 0; dt < 8; dt++) o[dt] = (f32x4){0.f, 0.f, 0.f, 0.f};
    float lpart = 0.f;   // per-lane partial row-sum for q-row l16

    const float scale2 = 0.12751743f;   // (1/sqrt(128)) * log2(e)
    const float C2 = 14.4269504f;       // 10 * log2(e)

    const u16* kgb = qkv + (size_t)(b * SEQ) * QKV_N + 2048 + kvh * HD;
    const u16* vgb = vt + (size_t)((b * NKV + kvh) * HD) * SEQ;
    const u64* mpb = mp + b * (SEQ / 64);

    int kr = t >> 4, kc = (t & 15) * 8;   // K: 16 chunks per 128-col row
    int vr = t >> 3, vc = (t & 7) * 8;    // V: 8 chunks per 64-col row
    int kb_end = (qt + 1) * 128;

    short8 k0p, k1p, v0p, v1p;
    {
        k0p = *(const short8*)(kgb + (size_t)kr * QKV_N + kc);
        k1p = *(const short8*)(kgb + (size_t)(kr + 32) * QKV_N + kc);
        v0p = *(const short8*)(vgb + (size_t)vr * SEQ + vc);
        v1p = *(const short8*)(vgb + (size_t)(vr + 64) * SEQ + vc);
    }

    for (int kb = 0; kb < kb_end; kb += 64) {
        __syncthreads();  // previous iter's LDS reads done
        *(short8*)(&Ks[kr][kc]) = k0p;
        *(short8*)(&Ks[kr + 32][kc]) = k1p;
        *(short8*)(&Vs[vr][vc]) = v0p;
        *(short8*)(&Vs[vr + 64][vc]) = v1p;
        __syncthreads();
        if (kb + 64 < kb_end) {  // prefetch next tile during compute (T14 issue-early)
            const u16* kg = kgb + (size_t)(kb + 64) * QKV_N;
            const u16* vg = vgb + kb + 64;
            k0p = *(const short8*)(kg + (size_t)kr * QKV_N + kc);
            k1p = *(const short8*)(kg + (size_t)(kr + 32) * QKV_N + kc);
            v0p = *(const short8*)(vg + (size_t)vr * SEQ + vc);
            v1p = *(const short8*)(vg + (size_t)(vr + 64) * SEQ + vc);
        }
        if (kb > q_row0 + 15) continue;  // wave-uniform: no keys for this wave's rows

        u64 mk = mpb[kb >> 6];   // wave-uniform mask bits for keys kb..kb+63

        // ---- scores (swapped): sc[nt][r] = S[key=kb+nt*16+quad*4+r][qrow=l16]
        f32x4 sc[4];
#pragma unroll
        for (int nt = 0; nt < 4; nt++) sc[nt] = (f32x4){0.f, 0.f, 0.f, 0.f};
        __builtin_amdgcn_s_setprio(1);
#pragma unroll
        for (int c = 0; c < 4; c++) {
#pragma unroll
            for (int nt = 0; nt < 4; nt++) {
                short8 kf = *(const short8*)(&Ks[nt * 16 + l16][c * 32 + quad * 8]);
                sc[nt] = __builtin_amdgcn_mfma_f32_16x16x32_bf16(kf, qf[c], sc[nt], 0, 0, 0);
            }
        }
        __builtin_amdgcn_s_setprio(0);

        // early V fragments (keys 0..31, dims 0..63): independent of softmax
        short8 vf0a[4];
#pragma unroll
        for (int dt = 0; dt < 4; dt++)
            vf0a[dt] = *(const short8*)(&Vs[dt * 16 + l16][quad * 8]);

        // ---- fixed-shift exp; fast path for fully-valid tiles (wave-uniform)
        float p[4][4];
        if (mk == ~0ull && kb + 63 <= q_row0) {
#pragma unroll
            for (int nt = 0; nt < 4; nt++)
#pragma unroll
                for (int r = 0; r < 4; r++)
                    p[nt][r] = __builtin_exp2f(__builtin_fmaf(sc[nt][r], scale2, -C2));
        } else {
            int limit = q_row0 + l16 - kb;   // keep iff bp <= limit (causal)
#pragma unroll
            for (int nt = 0; nt < 4; nt++) {
                unsigned nib = (unsigned)(mk >> (nt * 16 + quad * 4));
#pragma unroll
                for (int r = 0; r < 4; r++) {
                    int bp = nt * 16 + quad * 4 + r;
                    bool ok = ((nib >> r) & 1u) && (bp <= limit);
                    float v = ok ? sc[nt][r] : -INFINITY;
                    p[nt][r] = __builtin_exp2f(__builtin_fmaf(v, scale2, -C2));
                }
            }
        }
        lpart += ((p[0][0] + p[0][1]) + (p[0][2] + p[0][3])) +
                 ((p[1][0] + p[1][1]) + (p[1][2] + p[1][3])) +
                 ((p[2][0] + p[2][1]) + (p[2][2] + p[2][3])) +
                 ((p[3][0] + p[3][1]) + (p[3][2] + p[3][3]));

        // ---- T12: pack to bf16 and redistribute quads in-register.
        unsigned A0, A1, B0, B1, C0, C1, E0, E1;
        asm("v_cvt_pk_bf16_f32 %0, %1, %2" : "=v"(A0) : "v"(p[0][0]), "v"(p[0][1]));
        asm("v_cvt_pk_bf16_f32 %0, %1, %2" : "=v"(A1) : "v"(p[0][2]), "v"(p[0][3]));
        asm("v_cvt_pk_bf16_f32 %0, %1, %2" : "=v"(B0) : "v"(p[1][0]), "v"(p[1][1]));
        asm("v_cvt_pk_bf16_f32 %0, %1, %2" : "=v"(B1) : "v"(p[1][2]), "v"(p[1][3]));
        asm("v_cvt_pk_bf16_f32 %0, %1, %2" : "=v"(C0) : "v"(p[2][0]), "v"(p[2][1]));
        asm("v_cvt_pk_bf16_f32 %0, %1, %2" : "=v"(C1) : "v"(p[2][2]), "v"(p[2][3]));
        asm("v_cvt_pk_bf16_f32 %0, %1, %2" : "=v"(E0) : "v"(p[3][0]), "v"(p[3][1]));
        asm("v_cvt_pk_bf16_f32 %0, %1, %2" : "=v"(E1) : "v"(p[3][2]), "v"(p[3][3]));
        asm("v_permlane32_swap_b32 %0, %1" : "+v"(A0), "+v"(B0));
        asm("v_permlane16_swap_b32 %0, %1" : "+v"(A0), "+v"(B0));  // A0=D0, B0=D2
        asm("v_permlane32_swap_b32 %0, %1" : "+v"(A1), "+v"(B1));
        asm("v_permlane16_swap_b32 %0, %1" : "+v"(A1), "+v"(B1));  // A1=D1, B1=D3
        asm("v_permlane32_swap_b32 %0, %1" : "+v"(C0), "+v"(E0));
        asm("v_permlane16_swap_b32 %0, %1" : "+v"(C0), "+v"(E0));
        asm("v_permlane32_swap_b32 %0, %1" : "+v"(C1), "+v"(E1));
        asm("v_permlane16_swap_b32 %0, %1" : "+v"(C1), "+v"(E1));
        short8 pf0 = __builtin_bit_cast(short8, (uint4v){A0, A1, B0, B1});
        short8 pf1 = __builtin_bit_cast(short8, (uint4v){C0, C1, E0, E1});

        __builtin_amdgcn_s_setprio(1);
#pragma unroll
        for (int dt = 0; dt < 4; dt++)
            o[dt] = __builtin_amdgcn_mfma_f32_16x16x32_bf16(pf0, vf0a[dt], o[dt], 0, 0, 0);
#pragma unroll
        for (int dt = 4; dt < 8; dt++) {
            short8 vf0 = *(const short8*)(&Vs[dt * 16 + l16][quad * 8]);
            o[dt] = __builtin_amdgcn_mfma_f32_16x16x32_bf16(pf0, vf0, o[dt], 0, 0, 0);
        }
#pragma unroll
        for (int dt = 0; dt < 8; dt++) {
            short8 vf1 = *(const short8*)(&Vs[dt * 16 + l16][32 + quad * 8]);
            o[dt] = __builtin_amdgcn_mfma_f32_16x16x32_bf16(pf1, vf1, o[dt], 0, 0, 0);
        }
        __builtin_amdgcn_s_setprio(0);
    }
    // epilogue: full row-sum for q-row l16, then redistribute to output rows.
    float l = lpart;
    l += __shfl_xor(l, 16, 64);
    l += __shfl_xor(l, 32, 64);   // every lane: sum for q-row l16
    float invq[4];
#pragma unroll
    for (int r = 0; r < 4; r++) {
        float lr = __shfl(l, quad * 4 + r, 16);   // sum for q-row quad*4+r
        invq[r] = lr > 0.f ? 1.f / lr : 0.f;
    }
    size_t obase = (size_t)(b * SEQ + q_row0) * HIDDEN + h * HD;
#pragma unroll
    for (int dt = 0; dt < 8; dt++)
#pragma unroll
        for (int r = 0; r < 4; r++)
            attn[obase + (size_t)(quad * 4 + r) * HIDDEN + dt * 16 + l16] =
                f2bf(o[dt][r] * invq[r]);
}

extern "C" void kernel_launch(void* const* d_in, const int* in_sizes, int n_in,
                              void* d_out, int out_size, void* d_ws, size_t ws_size,
                              hipStream_t stream) {
    const float* hidden = (const float*)d_in[0];
    const int* amask   = (const int*)d_in[1];
    const float* Wq = (const float*)d_in[2];
    const float* bq = (const float*)d_in[3];
    const float* Wk = (const float*)d_in[4];
    const float* bk = (const float*)d_in[5];
    const float* Wv = (const float*)d_in[6];
    const float* bv = (const float*)d_in[7];
    const float* Wo = (const float*)d_in[8];
    const float* bo = (const float*)d_in[9];
    float* out = (float*)d_out;

    // workspace layout (~84 MB)
    char* ws = (char*)d_ws;
    u16* xb     = (u16*)ws;  ws += (size_t)MROWS * HIDDEN * 2;        // 16.8 MB
    u16* wqkvT  = (u16*)ws;  ws += (size_t)QKV_N * HIDDEN * 2;       // 12.6 MB
    u16* woT    = (u16*)ws;  ws += (size_t)HIDDEN * HIDDEN * 2;      // 8.4 MB
    float* bqkv = (float*)ws; ws += (size_t)QKV_N * 4;               // 12 KB
    u64* mpk    = (u64*)ws;  ws += (size_t)(MROWS / 64) * 8;         // 512 B
    u16* qkv    = (u16*)ws;  ws += (size_t)MROWS * QKV_N * 2;        // 25.2 MB
    u16* vt     = (u16*)ws;  ws += (size_t)BATCH * NKV * HD * SEQ * 2; // 4.2 MB
    u16* attn   = (u16*)ws;  ws += (size_t)MROWS * HIDDEN * 2;       // 16.8 MB

    // 1. fused prep (convert + 4 transposes + bias + mask) -- one dispatch
    prep<<<dim3(PREP_TOTAL), dim3(256), 0, stream>>>(
        hidden, xb, Wq, Wk, Wv, Wo, wqkvT, woT, bq, bk, bv, bqkv, amask, mpk);

    // 2. fused QKV projection (256^2 8-phase)
    gemm_bf16_256<true><<<dim3(QKV_N / 256, MROWS / 256), dim3(512), 0, stream>>>(
        xb, wqkvT, bqkv, qkv, MROWS, QKV_N, HIDDEN);

    // 3. V^T
    vt_from_qkv<<<dim3(SEQ / 32, HD / 32, BATCH * NKV), dim3(32, 8), 0, stream>>>(qkv, vt);

    // 4. attention (128 q rows per block, 8 waves x 16 rows, complementary pairing)
    flash_attn<<<dim3(SEQ / 128, NH, BATCH), dim3(512), 0, stream>>>(qkv, vt, mpk, attn);

    // 5. output projection (256^2 8-phase, fp32 out)
    gemm_bf16_256<false><<<dim3(HIDDEN / 256, MROWS / 256), dim3(512), 0, stream>>>(
        attn, woT, bo, out, MROWS, HIDDEN, HIDDEN);
}